// Round 3
// baseline (1019.436 us; speedup 1.0000x reference)
//
#include <hip/hip_runtime.h>
#include <hip/hip_bf16.h>

typedef __hip_bfloat16 bf16;

#define N_NODES 16384
#define D_FIL 512
#define D_IN 532
#define D_MODEL 1024
#define NHEAD 16
#define D_KEY 64
#define DFF 4096
#define NTREE 128
#define MEM_SLOTS 8
#define NODES_PER_TREE 128
#define EPS 1e-5f
#define ZLD 536  // z leading dim (532 + 4 pad)

__device__ inline float bf2f(unsigned short u) {
    union { unsigned int i; float f; } v; v.i = ((unsigned int)u) << 16; return v.f;
}
__device__ inline float bf2f(bf16 x) { return __bfloat162float(x); }

__device__ inline float gelu_exact(float x) {
    return 0.5f * x * (1.0f + erff(x * 0.7071067811865476f));
}

// block-wide (256 threads) simultaneous sum of two values
__device__ inline void blockReduceSum2(float& a, float& b, float* sm) {
    int tid = threadIdx.x;
    int lane = tid & 63, wid = tid >> 6;
#pragma unroll
    for (int off = 32; off > 0; off >>= 1) {
        a += __shfl_down(a, off, 64);
        b += __shfl_down(b, off, 64);
    }
    if (lane == 0) { sm[wid] = a; sm[4 + wid] = b; }
    __syncthreads();
    if (tid == 0) {
        sm[8] = sm[0] + sm[1] + sm[2] + sm[3];
        sm[9] = sm[4] + sm[5] + sm[6] + sm[7];
    }
    __syncthreads();
    a = sm[8]; b = sm[9];
}

// ---------------- wq[h][j] = sum_d q[h][d] * Wk[h*64+d][j] ----------------
__global__ void wq_kernel(const float* __restrict__ q, const float* __restrict__ Wk,
                          float* __restrict__ wq) {
    int h = blockIdx.x, tid = threadIdx.x;
    __shared__ float qs[64];
    if (tid < 64) qs[tid] = q[h * 64 + tid];
    __syncthreads();
    for (int j = tid; j < D_IN; j += 256) {
        float acc = 0.f;
#pragma unroll 8
        for (int d = 0; d < 64; ++d)
            acc += qs[d] * Wk[(size_t)(h * 64 + d) * D_IN + j];
        wq[h * D_IN + j] = acc;
    }
}

// ------------- per-node: LN(values) ++ tpd -> LN -> x(bf16) ; qkm ; bucket -------------
__global__ void node_prep_kernel(const float* __restrict__ values, const int* __restrict__ role,
                                 const int* __restrict__ bidx, const int* __restrict__ midx,
                                 const float* __restrict__ g_fil, const float* __restrict__ b_fil,
                                 const float* __restrict__ g_mha, const float* __restrict__ b_mha,
                                 const float* __restrict__ wq,
                                 bf16* __restrict__ x_out, float* __restrict__ qkm,
                                 int* __restrict__ counts, int* __restrict__ node_list) {
    int n = blockIdx.x, tid = threadIdx.x;
    __shared__ float y[D_IN];
    __shared__ float sm[16];

    float v0 = values[(size_t)n * D_FIL + tid];
    float v1 = values[(size_t)n * D_FIL + 256 + tid];
    float s = v0 + v1, ss = v0 * v0 + v1 * v1;
    blockReduceSum2(s, ss, sm);
    float mu = s * (1.f / D_FIL);
    float var = ss * (1.f / D_FIL) - mu * mu;
    float rs = rsqrtf(var + EPS);
    y[tid] = (v0 - mu) * rs * g_fil[tid] + b_fil[tid];
    y[tid + 256] = (v1 - mu) * rs * g_fil[tid + 256] + b_fil[tid + 256];
    if (tid < 20) {
        int r = role[n];
        int cm = 31 - __clz(r);     // highest set bit (r >= 1)
        int bit = (r >> tid) & 1;
        y[512 + tid] = (tid < cm) ? (bit ? 1.f : -1.f) : 0.f;
    }
    __syncthreads();

    float e0 = y[tid], e1 = y[tid + 256], e2 = (tid < 20) ? y[512 + tid] : 0.f;
    s = e0 + e1 + e2; ss = e0 * e0 + e1 * e1 + e2 * e2;
    blockReduceSum2(s, ss, sm);
    mu = s * (1.f / D_IN);
    var = ss * (1.f / D_IN) - mu * mu;
    rs = rsqrtf(var + EPS);
    float x0 = (e0 - mu) * rs * g_mha[tid] + b_mha[tid];
    float x1 = (e1 - mu) * rs * g_mha[tid + 256] + b_mha[tid + 256];
    y[tid] = x0; y[tid + 256] = x1;
    x_out[(size_t)n * D_IN + tid] = __float2bfloat16(x0);
    x_out[(size_t)n * D_IN + tid + 256] = __float2bfloat16(x1);
    if (tid < 20) {
        float x2 = (e2 - mu) * rs * g_mha[512 + tid] + b_mha[512 + tid];
        y[512 + tid] = x2;
        x_out[(size_t)n * D_IN + 512 + tid] = __float2bfloat16(x2);
    }
    __syncthreads();

    // qkm[n][h] = y . wq[h]   (full fp32 x, pre-rounding)
    int h = tid >> 4, sl = tid & 15;
    float acc = 0.f;
    for (int j = sl; j < D_IN; j += 16) acc += y[j] * wq[h * D_IN + j];
#pragma unroll
    for (int off = 8; off > 0; off >>= 1) acc += __shfl_down(acc, off, 16);
    if (sl == 0) qkm[(size_t)n * NHEAD + h] = acc;

    if (tid == 0) {
        int slot = bidx[n] * MEM_SLOTS + midx[n];
        int pos = atomicAdd(&counts[slot], 1);
        node_list[slot * NODES_PER_TREE + pos] = n;
    }
}

// ------- per-tree: softmax(qkm) -> a[128,16]; z = a^T X_t; out = per-head z.Wv -------
__global__ void attn_kernel(const int* __restrict__ node_list, const float* __restrict__ qkm,
                            const bf16* __restrict__ xb, const float* __restrict__ Wv,
                            float* __restrict__ out) {
    int t = blockIdx.x, tid = threadIdx.x;
    __shared__ int nodes[NODES_PER_TREE];
    __shared__ float a[NODES_PER_TREE * NHEAD];   // a[i*16+h]
    __shared__ float z[NHEAD * ZLD];              // z[h*ZLD+j]
    if (tid < NODES_PER_TREE) nodes[tid] = node_list[t * NODES_PER_TREE + tid];
    __syncthreads();
    for (int l = tid; l < NODES_PER_TREE * NHEAD; l += 256) {
        int i = l >> 4, h = l & 15;
        a[l] = qkm[(size_t)nodes[i] * NHEAD + h] * 0.125f;  // /sqrt(64)
    }
    __syncthreads();

    int grp = tid >> 4, sl = tid & 15;  // grp = head for softmax & gemv phases
    {
        float m = -1e30f;
        for (int i = sl; i < NODES_PER_TREE; i += 16) m = fmaxf(m, a[i * 16 + grp]);
#pragma unroll
        for (int off = 8; off > 0; off >>= 1) m = fmaxf(m, __shfl_down(m, off, 16));
        m = __shfl(m, 0, 16);
        float sum = 0.f;
        for (int i = sl; i < NODES_PER_TREE; i += 16) {
            float e = expf(a[i * 16 + grp] - m);
            a[i * 16 + grp] = e;
            sum += e;
        }
#pragma unroll
        for (int off = 8; off > 0; off >>= 1) sum += __shfl_down(sum, off, 16);
        sum = __shfl(sum, 0, 16);
        float inv = 1.0f / sum;
        for (int i = sl; i < NODES_PER_TREE; i += 16) a[i * 16 + grp] *= inv;
    }
    __syncthreads();

    // z[h][j] = sum_i a[i][h] * x[nodes[i]][j] ; thread owns j = tid, tid+256, (tid+512)
    {
        float az0[NHEAD] = {}, az1[NHEAD] = {}, az2[NHEAD] = {};
        int j2 = tid + 512;
        bool has2 = (j2 < D_IN);
        for (int i = 0; i < NODES_PER_TREE; ++i) {
            const bf16* xr = xb + (size_t)nodes[i] * D_IN;
            float xv0 = bf2f(xr[tid]);
            float xv1 = bf2f(xr[tid + 256]);
            float xv2 = has2 ? bf2f(xr[j2]) : 0.f;
#pragma unroll
            for (int h = 0; h < NHEAD; ++h) {
                float w = a[i * 16 + h];
                az0[h] += w * xv0;
                az1[h] += w * xv1;
                az2[h] += w * xv2;
            }
        }
#pragma unroll
        for (int h = 0; h < NHEAD; ++h) {
            z[h * ZLD + tid] = az0[h];
            z[h * ZLD + tid + 256] = az1[h];
            if (has2) z[h * ZLD + j2] = az2[h];
        }
    }
    __syncthreads();

    // out[t][c] = sum_j z[c>>6][j] * Wv[c*532+j]; group grp handles cols [grp*64, grp*64+64)
#pragma unroll 4
    for (int it = 0; it < 64; ++it) {
        int c = grp * 64 + it;
        const float* wr = Wv + (size_t)c * D_IN;
        const float* zr = z + grp * ZLD;
        float acc = 0.f;
        for (int j = sl; j < D_IN; j += 16) acc += zr[j] * wr[j];
#pragma unroll
        for (int off = 8; off > 0; off >>= 1) acc += __shfl_down(acc, off, 16);
        if (sl == 0) out[(size_t)t * D_MODEL + c] = acc;
    }
}

// ---------------- small GEMM: C[128,N] = A[128,K] @ B[N,K]^T + epilogue ----------------
// MODE 0: + bias + addb (r1);  MODE 1: gelu(+bias);  MODE 2: + bias + addf[row*1024+col]
template <int MODE>
__global__ void gemm_small_kernel(const float* __restrict__ A, const float* __restrict__ B,
                                  float* __restrict__ C, int N, int K,
                                  const float* __restrict__ bias, const float* __restrict__ addb,
                                  const float* __restrict__ addf) {
    __shared__ float As[32 * 34];
    __shared__ float Bs[32 * 66];
    int tid = threadIdx.x;
    int row0 = blockIdx.y * 32, col0 = blockIdx.x * 64;
    int ai = tid >> 3, aka = (tid & 7) * 4;
    int bj = tid >> 2, bk = (tid & 3) * 8;
    int ty = tid >> 4, tx = tid & 15;

    float acc[2][4] = {};
    const float* Arow = A + (size_t)(row0 + ai) * K;
    const float* Brow = B + (size_t)(col0 + bj) * K;

    int nkb = K / 32;
    for (int kb = 0; kb < nkb; ++kb) {
        int kbase = kb * 32;
        float4 fa = *(const float4*)(Arow + kbase + aka);
        As[(aka + 0) * 34 + ai] = fa.x; As[(aka + 1) * 34 + ai] = fa.y;
        As[(aka + 2) * 34 + ai] = fa.z; As[(aka + 3) * 34 + ai] = fa.w;
        float4 f0 = *(const float4*)(Brow + kbase + bk);
        float4 f1 = *(const float4*)(Brow + kbase + bk + 4);
        Bs[(bk + 0) * 66 + bj] = f0.x; Bs[(bk + 1) * 66 + bj] = f0.y;
        Bs[(bk + 2) * 66 + bj] = f0.z; Bs[(bk + 3) * 66 + bj] = f0.w;
        Bs[(bk + 4) * 66 + bj] = f1.x; Bs[(bk + 5) * 66 + bj] = f1.y;
        Bs[(bk + 6) * 66 + bj] = f1.z; Bs[(bk + 7) * 66 + bj] = f1.w;
        __syncthreads();
#pragma unroll
        for (int k = 0; k < 32; ++k) {
            float a0 = As[k * 34 + ty * 2 + 0], a1 = As[k * 34 + ty * 2 + 1];
            float b0 = Bs[k * 66 + tx * 4 + 0], b1 = Bs[k * 66 + tx * 4 + 1];
            float b2 = Bs[k * 66 + tx * 4 + 2], b3 = Bs[k * 66 + tx * 4 + 3];
            acc[0][0] += a0 * b0; acc[0][1] += a0 * b1; acc[0][2] += a0 * b2; acc[0][3] += a0 * b3;
            acc[1][0] += a1 * b0; acc[1][1] += a1 * b1; acc[1][2] += a1 * b2; acc[1][3] += a1 * b3;
        }
        __syncthreads();
    }
#pragma unroll
    for (int r = 0; r < 2; ++r)
#pragma unroll
        for (int c = 0; c < 4; ++c) {
            int row = row0 + ty * 2 + r, col = col0 + tx * 4 + c;
            float val = acc[r][c] + bias[col];
            if (MODE == 0) val += addb[col];
            if (MODE == 1) val = gelu_exact(val);
            if (MODE == 2) val += addf[(size_t)row * D_MODEL + col];
            C[(size_t)row * N + col] = val;
        }
}

// ---------------- LayerNorm over 1024, fp32 out; optionally zero mask tail ----------------
__global__ void ln1024_kernel(const float* __restrict__ in, const float* __restrict__ g,
                              const float* __restrict__ b, float* __restrict__ outf,
                              int zeroTail) {
    int t = blockIdx.x, tid = threadIdx.x;
    __shared__ float sm[16];
    float e[4];
#pragma unroll
    for (int c = 0; c < 4; ++c) e[c] = in[(size_t)t * D_MODEL + c * 256 + tid];
    float s = e[0] + e[1] + e[2] + e[3];
    float ss = e[0] * e[0] + e[1] * e[1] + e[2] * e[2] + e[3] * e[3];
    blockReduceSum2(s, ss, sm);
    float mu = s * (1.f / D_MODEL);
    float var = ss * (1.f / D_MODEL) - mu * mu;
    float rs = rsqrtf(var + EPS);
#pragma unroll
    for (int c = 0; c < 4; ++c) {
        int j = c * 256 + tid;
        outf[(size_t)t * D_MODEL + j] = (e[c] - mu) * rs * g[j] + b[j];
    }
    if (zeroTail && t == 0 && tid < 128) outf[(size_t)NTREE * D_MODEL + tid] = 0.f;
}

extern "C" void kernel_launch(void* const* d_in, const int* in_sizes, int n_in,
                              void* d_out, int out_size, void* d_ws, size_t ws_size,
                              hipStream_t stream) {
    const float* values = (const float*)d_in[0];
    const int* role     = (const int*)d_in[1];
    const int* bidx     = (const int*)d_in[2];
    const int* midx     = (const int*)d_in[3];
    const float* qvec   = (const float*)d_in[4];
    const float* Wk     = (const float*)d_in[5];
    const float* Wv     = (const float*)d_in[6];
    const float* Wo     = (const float*)d_in[7];
    const float* bo     = (const float*)d_in[8];
    const float* W1     = (const float*)d_in[9];
    const float* b1     = (const float*)d_in[10];
    const float* W2     = (const float*)d_in[11];
    const float* b2     = (const float*)d_in[12];
    const float* g_fil  = (const float*)d_in[13];
    const float* b_fil  = (const float*)d_in[14];
    const float* g_mha  = (const float*)d_in[15];
    const float* b_mha  = (const float*)d_in[16];
    const float* g_ff   = (const float*)d_in[17];
    const float* b_ff   = (const float*)d_in[18];
    const float* g_out  = (const float*)d_in[19];
    const float* b_out  = (const float*)d_in[20];

    // workspace layout (total ~22.8 MB)
    char* w = (char*)d_ws;
    float* wq       = (float*)(w + 0);          // 16*532*4 = 34048 (pad to 34816)
    float* qkm      = (float*)(w + 34816);      // 16384*16*4 = 1048576
    int*   node_list= (int*)  (w + 1083392);    // 16384*4 = 65536
    int*   counts   = (int*)  (w + 1148928);    // 512 (pad to 1024)
    float* attn_out = (float*)(w + 1149952);    // 128*1024*4 = 524288
    float* r1       = (float*)(w + 1674240);    // 524288
    float* l1       = (float*)(w + 2198528);    // 524288
    float* h1       = (float*)(w + 2722816);    // 128*4096*4 = 2097152
    float* ff       = (float*)(w + 4819968);    // 524288
    bf16*  xb       = (bf16*) (w + 5344256);    // 16384*532*2 = 17432576 -> ends 22776832

    float* out = (float*)d_out;  // [128*1024] rectangle_out fp32 ++ [128] pad mask (zeros)

    hipMemsetAsync(counts, 0, 128 * sizeof(int), stream);

    wq_kernel<<<16, 256, 0, stream>>>(qvec, Wk, wq);

    node_prep_kernel<<<N_NODES, 256, 0, stream>>>(values, role, bidx, midx,
                                                  g_fil, b_fil, g_mha, b_mha,
                                                  wq, xb, qkm, counts, node_list);

    attn_kernel<<<NTREE, 256, 0, stream>>>(node_list, qkm, xb, Wv, attn_out);

    gemm_small_kernel<0><<<dim3(D_MODEL / 64, NTREE / 32), 256, 0, stream>>>(
        attn_out, Wo, r1, D_MODEL, D_MODEL, bo, qvec, nullptr);

    ln1024_kernel<<<NTREE, 256, 0, stream>>>(r1, g_ff, b_ff, l1, 0);

    gemm_small_kernel<1><<<dim3(DFF / 64, NTREE / 32), 256, 0, stream>>>(
        l1, W1, h1, DFF, D_MODEL, b1, nullptr, nullptr);

    gemm_small_kernel<2><<<dim3(D_MODEL / 64, NTREE / 32), 256, 0, stream>>>(
        h1, W2, ff, D_MODEL, DFF, b2, nullptr, r1);

    ln1024_kernel<<<NTREE, 256, 0, stream>>>(ff, g_out, b_out, out, 1);
}

// Round 4
// 783.424 us; speedup vs baseline: 1.3013x; 1.3013x over previous
//
#include <hip/hip_runtime.h>
#include <hip/hip_bf16.h>

typedef __hip_bfloat16 bf16;

#define N_NODES 16384
#define D_FIL 512
#define D_IN 532
#define D_MODEL 1024
#define NHEAD 16
#define D_KEY 64
#define DFF 4096
#define NTREE 128
#define MEM_SLOTS 8
#define NODES_PER_TREE 128
#define EPS 1e-5f
#define ZLD 532          // zbuf row stride (fp32)
#define ZSLD 536         // contract-kernel LDS row stride

__device__ inline float bf2f(unsigned short u) {
    union { unsigned int i; float f; } v; v.i = ((unsigned int)u) << 16; return v.f;
}
__device__ inline float bf2f(bf16 x) { return __bfloat162float(x); }

__device__ inline float gelu_exact(float x) {
    return 0.5f * x * (1.0f + erff(x * 0.7071067811865476f));
}

// block-wide (256 threads) simultaneous sum of two values
__device__ inline void blockReduceSum2(float& a, float& b, float* sm) {
    int tid = threadIdx.x;
    int lane = tid & 63, wid = tid >> 6;
#pragma unroll
    for (int off = 32; off > 0; off >>= 1) {
        a += __shfl_down(a, off, 64);
        b += __shfl_down(b, off, 64);
    }
    if (lane == 0) { sm[wid] = a; sm[4 + wid] = b; }
    __syncthreads();
    if (tid == 0) {
        sm[8] = sm[0] + sm[1] + sm[2] + sm[3];
        sm[9] = sm[4] + sm[5] + sm[6] + sm[7];
    }
    __syncthreads();
    a = sm[8]; b = sm[9];
}

// ---------------- wq[h][j] = sum_d q[h][d] * Wk[h*64+d][j] ----------------
__global__ void wq_kernel(const float* __restrict__ q, const float* __restrict__ Wk,
                          float* __restrict__ wq) {
    int h = blockIdx.x, jc = blockIdx.y, tid = threadIdx.x;
    __shared__ float qs[64];
    if (tid < 64) qs[tid] = q[h * 64 + tid];
    __syncthreads();
    int jend = jc * 133 + 133;
    for (int j = jc * 133 + tid; j < jend; j += 256) {
        float acc = 0.f;
#pragma unroll 8
        for (int d = 0; d < 64; ++d)
            acc += qs[d] * Wk[(size_t)(h * 64 + d) * D_IN + j];
        wq[h * D_IN + j] = acc;
    }
}

// ------------- per-node: LN(values) ++ tpd -> LN -> xs(bf16, tree-permuted) ; qkmp -------------
__global__ void node_prep_kernel(const float* __restrict__ values, const int* __restrict__ role,
                                 const int* __restrict__ bidx, const int* __restrict__ midx,
                                 const float* __restrict__ g_fil, const float* __restrict__ b_fil,
                                 const float* __restrict__ g_mha, const float* __restrict__ b_mha,
                                 const float* __restrict__ wq,
                                 bf16* __restrict__ xs, float* __restrict__ qkmp,
                                 int* __restrict__ counts) {
    int n = blockIdx.x, tid = threadIdx.x;
    __shared__ float y[D_IN];
    __shared__ float sm[16];
    __shared__ int rowS;
    if (tid == 0) {
        int slot = bidx[n] * MEM_SLOTS + midx[n];
        int pos = atomicAdd(&counts[slot], 1);
        rowS = slot * NODES_PER_TREE + pos;
    }

    float v0 = values[(size_t)n * D_FIL + tid];
    float v1 = values[(size_t)n * D_FIL + 256 + tid];
    float s = v0 + v1, ss = v0 * v0 + v1 * v1;
    blockReduceSum2(s, ss, sm);
    float mu = s * (1.f / D_FIL);
    float var = ss * (1.f / D_FIL) - mu * mu;
    float rs = rsqrtf(var + EPS);
    y[tid] = (v0 - mu) * rs * g_fil[tid] + b_fil[tid];
    y[tid + 256] = (v1 - mu) * rs * g_fil[tid + 256] + b_fil[tid + 256];
    if (tid < 20) {
        int r = role[n];
        int cm = 31 - __clz(r);     // highest set bit (r >= 1)
        int bit = (r >> tid) & 1;
        y[512 + tid] = (tid < cm) ? (bit ? 1.f : -1.f) : 0.f;
    }
    __syncthreads();

    int row = rowS;
    float e0 = y[tid], e1 = y[tid + 256], e2 = (tid < 20) ? y[512 + tid] : 0.f;
    s = e0 + e1 + e2; ss = e0 * e0 + e1 * e1 + e2 * e2;
    blockReduceSum2(s, ss, sm);
    mu = s * (1.f / D_IN);
    var = ss * (1.f / D_IN) - mu * mu;
    rs = rsqrtf(var + EPS);
    float x0 = (e0 - mu) * rs * g_mha[tid] + b_mha[tid];
    float x1 = (e1 - mu) * rs * g_mha[tid + 256] + b_mha[tid + 256];
    y[tid] = x0; y[tid + 256] = x1;
    bf16* xr = xs + (size_t)row * D_IN;
    xr[tid] = __float2bfloat16(x0);
    xr[tid + 256] = __float2bfloat16(x1);
    if (tid < 20) {
        float x2 = (e2 - mu) * rs * g_mha[512 + tid] + b_mha[512 + tid];
        y[512 + tid] = x2;
        xr[512 + tid] = __float2bfloat16(x2);
    }
    __syncthreads();

    // qkmp[row][h] = y . wq[h]   (full fp32 x, pre-rounding)
    int h = tid >> 4, sl = tid & 15;
    float acc = 0.f;
    for (int j = sl; j < D_IN; j += 16) acc += y[j] * wq[h * D_IN + j];
#pragma unroll
    for (int off = 8; off > 0; off >>= 1) acc += __shfl_down(acc, off, 16);
    if (sl == 0) qkmp[(size_t)row * NHEAD + h] = acc;
}

// ---------------- per-tree softmax over 128 members: aw[t][i][h] ----------------
__global__ void softmax_kernel(const float* __restrict__ qkmp, float* __restrict__ aw) {
    int t = blockIdx.x, tid = threadIdx.x;
    __shared__ float a[NODES_PER_TREE * NHEAD];
    for (int l = tid; l < NODES_PER_TREE * NHEAD; l += 256)
        a[l] = qkmp[(size_t)t * NODES_PER_TREE * NHEAD + l] * 0.125f;  // /sqrt(64)
    __syncthreads();

    int h = tid >> 4, sl = tid & 15;
    float m = -1e30f;
    for (int i = sl; i < NODES_PER_TREE; i += 16) m = fmaxf(m, a[i * 16 + h]);
#pragma unroll
    for (int off = 8; off > 0; off >>= 1) m = fmaxf(m, __shfl_down(m, off, 16));
    m = __shfl(m, 0, 16);
    float sum = 0.f;
    for (int i = sl; i < NODES_PER_TREE; i += 16) {
        float e = expf(a[i * 16 + h] - m);
        a[i * 16 + h] = e;
        sum += e;
    }
#pragma unroll
    for (int off = 8; off > 0; off >>= 1) sum += __shfl_down(sum, off, 16);
    sum = __shfl(sum, 0, 16);
    float inv = 1.0f / sum;
    for (int i = sl; i < NODES_PER_TREE; i += 16)
        aw[(size_t)t * NODES_PER_TREE * NHEAD + i * 16 + h] = a[i * 16 + h] * inv;
}

// ---------------- z[t][h][j] = sum_i aw[t][i][h] * xs[t*128+i][j] ----------------
// grid (4 head-groups, 128 trees); block 256
__global__ void z_kernel(const float* __restrict__ aw, const bf16* __restrict__ xs,
                         float* __restrict__ zbuf) {
    int hg = blockIdx.x, t = blockIdx.y, tid = threadIdx.x;
    __shared__ float a4[NODES_PER_TREE * 4];
    for (int l = tid; l < NODES_PER_TREE * 4; l += 256) {
        int i = l >> 2, hh = l & 3;
        a4[l] = aw[(size_t)t * NODES_PER_TREE * NHEAD + i * 16 + hg * 4 + hh];
    }
    __syncthreads();

    bool has2 = (tid + 512) < D_IN;
    float az[4][3] = {};
    const bf16* xt = xs + (size_t)t * NODES_PER_TREE * D_IN;
    for (int i = 0; i < NODES_PER_TREE; ++i) {
        const bf16* xr = xt + i * D_IN;
        float x0 = bf2f(xr[tid]);
        float x1 = bf2f(xr[tid + 256]);
        float x2 = has2 ? bf2f(xr[tid + 512]) : 0.f;
        float w0 = a4[i * 4 + 0], w1 = a4[i * 4 + 1];
        float w2 = a4[i * 4 + 2], w3 = a4[i * 4 + 3];
        az[0][0] += w0 * x0; az[0][1] += w0 * x1; az[0][2] += w0 * x2;
        az[1][0] += w1 * x0; az[1][1] += w1 * x1; az[1][2] += w1 * x2;
        az[2][0] += w2 * x0; az[2][1] += w2 * x1; az[2][2] += w2 * x2;
        az[3][0] += w3 * x0; az[3][1] += w3 * x1; az[3][2] += w3 * x2;
    }
#pragma unroll
    for (int hh = 0; hh < 4; ++hh) {
        float* zr = zbuf + (size_t)(t * NHEAD + hg * 4 + hh) * ZLD;
        zr[tid] = az[hh][0];
        zr[tid + 256] = az[hh][1];
        if (has2) zr[tid + 512] = az[hh][2];
    }
}

// ---------------- attn_out[t][c] = sum_j zbuf[t][c>>6][j] * Wv[c][j] ----------------
// grid (4 col-groups of 256, 128 trees); block 256
__global__ void contract_kernel(const float* __restrict__ zbuf, const float* __restrict__ Wv,
                                float* __restrict__ attn_out) {
    int cg = blockIdx.x, t = blockIdx.y, tid = threadIdx.x;
    __shared__ float zs[4 * ZSLD];
#pragma unroll
    for (int hh = 0; hh < 4; ++hh)
        for (int j = tid; j < D_IN; j += 256)
            zs[hh * ZSLD + j] = zbuf[(size_t)(t * NHEAD + cg * 4 + hh) * ZLD + j];
    __syncthreads();

    int grp = tid >> 4, sl = tid & 15;
#pragma unroll 2
    for (int it = 0; it < 16; ++it) {
        int lc = it * 16 + grp;            // 0..255 local col
        int c = cg * 256 + lc;
        const float* wr = Wv + (size_t)c * D_IN;
        const float* zr = zs + (lc >> 6) * ZSLD;
        float acc = 0.f;
        for (int j = sl; j < D_IN; j += 16) acc += zr[j] * wr[j];
#pragma unroll
        for (int off = 8; off > 0; off >>= 1) acc += __shfl_down(acc, off, 16);
        if (sl == 0) attn_out[(size_t)t * D_MODEL + c] = acc;
    }
}

// ---------------- GEMM: C[128,N] = A[128,K] @ B[N,K]^T + epilogue ----------------
// 64x64 tile, 4x4 per thread. MODE 0: +bias+addb; MODE 1: gelu(+bias); MODE 2: +bias+addf
template <int MODE>
__global__ void gemm64_kernel(const float* __restrict__ A, const float* __restrict__ B,
                              float* __restrict__ C, int N, int K,
                              const float* __restrict__ bias, const float* __restrict__ addb,
                              const float* __restrict__ addf) {
    __shared__ __align__(16) float As[32 * 68];
    __shared__ __align__(16) float Bs[32 * 68];
    int tid = threadIdx.x;
    int col0 = blockIdx.x * 64, row0 = blockIdx.y * 64;
    int ai = tid >> 2, ak = (tid & 3) * 8;
    int ty = tid >> 4, tx = tid & 15;

    float acc[4][4] = {};
    const float* Arow = A + (size_t)(row0 + ai) * K;
    const float* Brow = B + (size_t)(col0 + ai) * K;

    int nkb = K / 32;
    for (int kb = 0; kb < nkb; ++kb) {
        int kbase = kb * 32;
        float4 f0 = *(const float4*)(Arow + kbase + ak);
        float4 f1 = *(const float4*)(Arow + kbase + ak + 4);
        As[(ak + 0) * 68 + ai] = f0.x; As[(ak + 1) * 68 + ai] = f0.y;
        As[(ak + 2) * 68 + ai] = f0.z; As[(ak + 3) * 68 + ai] = f0.w;
        As[(ak + 4) * 68 + ai] = f1.x; As[(ak + 5) * 68 + ai] = f1.y;
        As[(ak + 6) * 68 + ai] = f1.z; As[(ak + 7) * 68 + ai] = f1.w;
        float4 g0 = *(const float4*)(Brow + kbase + ak);
        float4 g1 = *(const float4*)(Brow + kbase + ak + 4);
        Bs[(ak + 0) * 68 + ai] = g0.x; Bs[(ak + 1) * 68 + ai] = g0.y;
        Bs[(ak + 2) * 68 + ai] = g0.z; Bs[(ak + 3) * 68 + ai] = g0.w;
        Bs[(ak + 4) * 68 + ai] = g1.x; Bs[(ak + 5) * 68 + ai] = g1.y;
        Bs[(ak + 6) * 68 + ai] = g1.z; Bs[(ak + 7) * 68 + ai] = g1.w;
        __syncthreads();
#pragma unroll
        for (int k = 0; k < 32; ++k) {
            float4 av = *(const float4*)(As + k * 68 + ty * 4);
            float4 bv = *(const float4*)(Bs + k * 68 + tx * 4);
            acc[0][0] += av.x * bv.x; acc[0][1] += av.x * bv.y; acc[0][2] += av.x * bv.z; acc[0][3] += av.x * bv.w;
            acc[1][0] += av.y * bv.x; acc[1][1] += av.y * bv.y; acc[1][2] += av.y * bv.z; acc[1][3] += av.y * bv.w;
            acc[2][0] += av.z * bv.x; acc[2][1] += av.z * bv.y; acc[2][2] += av.z * bv.z; acc[2][3] += av.z * bv.w;
            acc[3][0] += av.w * bv.x; acc[3][1] += av.w * bv.y; acc[3][2] += av.w * bv.z; acc[3][3] += av.w * bv.w;
        }
        __syncthreads();
    }
#pragma unroll
    for (int r = 0; r < 4; ++r)
#pragma unroll
        for (int c = 0; c < 4; ++c) {
            int row = row0 + ty * 4 + r, col = col0 + tx * 4 + c;
            float val = acc[r][c] + bias[col];
            if (MODE == 0) val += addb[col];
            if (MODE == 1) val = gelu_exact(val);
            if (MODE == 2) val += addf[(size_t)row * D_MODEL + col];
            C[(size_t)row * N + col] = val;
        }
}

// ---------------- LayerNorm over 1024, fp32 out; optionally zero mask tail ----------------
__global__ void ln1024_kernel(const float* __restrict__ in, const float* __restrict__ g,
                              const float* __restrict__ b, float* __restrict__ outf,
                              int zeroTail) {
    int t = blockIdx.x, tid = threadIdx.x;
    __shared__ float sm[16];
    float e[4];
#pragma unroll
    for (int c = 0; c < 4; ++c) e[c] = in[(size_t)t * D_MODEL + c * 256 + tid];
    float s = e[0] + e[1] + e[2] + e[3];
    float ss = e[0] * e[0] + e[1] * e[1] + e[2] * e[2] + e[3] * e[3];
    blockReduceSum2(s, ss, sm);
    float mu = s * (1.f / D_MODEL);
    float var = ss * (1.f / D_MODEL) - mu * mu;
    float rs = rsqrtf(var + EPS);
#pragma unroll
    for (int c = 0; c < 4; ++c) {
        int j = c * 256 + tid;
        outf[(size_t)t * D_MODEL + j] = (e[c] - mu) * rs * g[j] + b[j];
    }
    if (zeroTail && t == 0 && tid < 128) outf[(size_t)NTREE * D_MODEL + tid] = 0.f;
}

extern "C" void kernel_launch(void* const* d_in, const int* in_sizes, int n_in,
                              void* d_out, int out_size, void* d_ws, size_t ws_size,
                              hipStream_t stream) {
    const float* values = (const float*)d_in[0];
    const int* role     = (const int*)d_in[1];
    const int* bidx     = (const int*)d_in[2];
    const int* midx     = (const int*)d_in[3];
    const float* qvec   = (const float*)d_in[4];
    const float* Wk     = (const float*)d_in[5];
    const float* Wv     = (const float*)d_in[6];
    const float* Wo     = (const float*)d_in[7];
    const float* bo     = (const float*)d_in[8];
    const float* W1     = (const float*)d_in[9];
    const float* b1     = (const float*)d_in[10];
    const float* W2     = (const float*)d_in[11];
    const float* b2     = (const float*)d_in[12];
    const float* g_fil  = (const float*)d_in[13];
    const float* b_fil  = (const float*)d_in[14];
    const float* g_mha  = (const float*)d_in[15];
    const float* b_mha  = (const float*)d_in[16];
    const float* g_ff   = (const float*)d_in[17];
    const float* b_ff   = (const float*)d_in[18];
    const float* g_out  = (const float*)d_in[19];
    const float* b_out  = (const float*)d_in[20];

    // workspace layout (~26.8 MB)
    char* w = (char*)d_ws;
    float* wq       = (float*)(w + 0);          // 16*532*4 = 34048 -> pad 34816
    float* qkmp     = (float*)(w + 34816);      // 16384*16*4 = 1048576
    int*   counts   = (int*)  (w + 1083392);    // 512 -> pad 1024
    float* aw       = (float*)(w + 1084416);    // 128*128*16*4 = 1048576
    float* zbuf     = (float*)(w + 2132992);    // 128*16*532*4 = 4358144
    float* attn_out = (float*)(w + 6491136);    // 128*1024*4 = 524288
    float* r1       = (float*)(w + 7015424);    // 524288
    float* l1       = (float*)(w + 7539712);    // 524288
    float* h1       = (float*)(w + 8064000);    // 128*4096*4 = 2097152
    float* ff       = (float*)(w + 10161152);   // 524288
    bf16*  xs       = (bf16*) (w + 10685440);   // 16384*532*2 = 17432576 -> ends 28118016

    float* out = (float*)d_out;  // [128*1024] rectangle_out fp32 ++ [128] pad mask (zeros)

    hipMemsetAsync(counts, 0, 128 * sizeof(int), stream);

    wq_kernel<<<dim3(16, 4), 256, 0, stream>>>(qvec, Wk, wq);

    node_prep_kernel<<<N_NODES, 256, 0, stream>>>(values, role, bidx, midx,
                                                  g_fil, b_fil, g_mha, b_mha,
                                                  wq, xs, qkmp, counts);

    softmax_kernel<<<NTREE, 256, 0, stream>>>(qkmp, aw);

    z_kernel<<<dim3(4, NTREE), 256, 0, stream>>>(aw, xs, zbuf);

    contract_kernel<<<dim3(4, NTREE), 256, 0, stream>>>(zbuf, Wv, attn_out);

    gemm64_kernel<0><<<dim3(D_MODEL / 64, 2), 256, 0, stream>>>(
        attn_out, Wo, r1, D_MODEL, D_MODEL, bo, qvec, nullptr);

    ln1024_kernel<<<NTREE, 256, 0, stream>>>(r1, g_ff, b_ff, l1, 0);

    gemm64_kernel<1><<<dim3(DFF / 64, 2), 256, 0, stream>>>(
        l1, W1, h1, DFF, D_MODEL, b1, nullptr, nullptr);

    gemm64_kernel<2><<<dim3(D_MODEL / 64, 2), 256, 0, stream>>>(
        h1, W2, ff, D_MODEL, DFF, b2, nullptr, r1);

    ln1024_kernel<<<NTREE, 256, 0, stream>>>(ff, g_out, b_out, out, 1);
}

// Round 5
// 503.651 us; speedup vs baseline: 2.0241x; 1.5555x over previous
//
#include <hip/hip_runtime.h>
#include <hip/hip_bf16.h>

typedef __hip_bfloat16 bf16;

#define N_NODES 16384
#define D_FIL 512
#define D_IN 532
#define D_MODEL 1024
#define NHEAD 16
#define D_KEY 64
#define DFF 4096
#define NTREE 128
#define MEM_SLOTS 8
#define NODES_PER_TREE 128
#define EPS 1e-5f
#define ZLD 532          // zbuf row stride (fp32)
#define ZSLD 536         // contract-kernel LDS row stride

__device__ inline float bf2f(unsigned short u) {
    union { unsigned int i; float f; } v; v.i = ((unsigned int)u) << 16; return v.f;
}
__device__ inline float bf2f(bf16 x) { return __bfloat162float(x); }

__device__ inline float gelu_exact(float x) {
    return 0.5f * x * (1.0f + erff(x * 0.7071067811865476f));
}

// block-wide (256 threads) simultaneous sum of two values
__device__ inline void blockReduceSum2(float& a, float& b, float* sm) {
    int tid = threadIdx.x;
    int lane = tid & 63, wid = tid >> 6;
#pragma unroll
    for (int off = 32; off > 0; off >>= 1) {
        a += __shfl_down(a, off, 64);
        b += __shfl_down(b, off, 64);
    }
    if (lane == 0) { sm[wid] = a; sm[4 + wid] = b; }
    __syncthreads();
    if (tid == 0) {
        sm[8] = sm[0] + sm[1] + sm[2] + sm[3];
        sm[9] = sm[4] + sm[5] + sm[6] + sm[7];
    }
    __syncthreads();
    a = sm[8]; b = sm[9];
}

// ---------------- wq[h][j] = sum_d q[h][d] * Wk[h*64+d][j] ----------------
__global__ void wq_kernel(const float* __restrict__ q, const float* __restrict__ Wk,
                          float* __restrict__ wq) {
    int h = blockIdx.x, jc = blockIdx.y, tid = threadIdx.x;
    __shared__ float qs[64];
    if (tid < 64) qs[tid] = q[h * 64 + tid];
    __syncthreads();
    int jend = jc * 133 + 133;
    for (int j = jc * 133 + tid; j < jend; j += 256) {
        float acc = 0.f;
#pragma unroll 8
        for (int d = 0; d < 64; ++d)
            acc += qs[d] * Wk[(size_t)(h * 64 + d) * D_IN + j];
        wq[h * D_IN + j] = acc;
    }
}

// ------------- per-node: LN(values) ++ tpd -> LN -> xs(bf16, tree-permuted) ; qkmp -------------
__global__ void node_prep_kernel(const float* __restrict__ values, const int* __restrict__ role,
                                 const int* __restrict__ bidx, const int* __restrict__ midx,
                                 const float* __restrict__ g_fil, const float* __restrict__ b_fil,
                                 const float* __restrict__ g_mha, const float* __restrict__ b_mha,
                                 const float* __restrict__ wq,
                                 bf16* __restrict__ xs, float* __restrict__ qkmp,
                                 int* __restrict__ counts) {
    int n = blockIdx.x, tid = threadIdx.x;
    __shared__ float y[D_IN];
    __shared__ float sm[16];
    __shared__ int rowS;
    if (tid == 0) {
        int slot = bidx[n] * MEM_SLOTS + midx[n];
        int pos = atomicAdd(&counts[slot], 1);
        rowS = slot * NODES_PER_TREE + pos;
    }

    float v0 = values[(size_t)n * D_FIL + tid];
    float v1 = values[(size_t)n * D_FIL + 256 + tid];
    float s = v0 + v1, ss = v0 * v0 + v1 * v1;
    blockReduceSum2(s, ss, sm);
    float mu = s * (1.f / D_FIL);
    float var = ss * (1.f / D_FIL) - mu * mu;
    float rs = rsqrtf(var + EPS);
    y[tid] = (v0 - mu) * rs * g_fil[tid] + b_fil[tid];
    y[tid + 256] = (v1 - mu) * rs * g_fil[tid + 256] + b_fil[tid + 256];
    if (tid < 20) {
        int r = role[n];
        int cm = 31 - __clz(r);     // highest set bit (r >= 1)
        int bit = (r >> tid) & 1;
        y[512 + tid] = (tid < cm) ? (bit ? 1.f : -1.f) : 0.f;
    }
    __syncthreads();

    int row = rowS;
    float e0 = y[tid], e1 = y[tid + 256], e2 = (tid < 20) ? y[512 + tid] : 0.f;
    s = e0 + e1 + e2; ss = e0 * e0 + e1 * e1 + e2 * e2;
    blockReduceSum2(s, ss, sm);
    mu = s * (1.f / D_IN);
    var = ss * (1.f / D_IN) - mu * mu;
    rs = rsqrtf(var + EPS);
    float x0 = (e0 - mu) * rs * g_mha[tid] + b_mha[tid];
    float x1 = (e1 - mu) * rs * g_mha[tid + 256] + b_mha[tid + 256];
    y[tid] = x0; y[tid + 256] = x1;
    bf16* xr = xs + (size_t)row * D_IN;
    xr[tid] = __float2bfloat16(x0);
    xr[tid + 256] = __float2bfloat16(x1);
    if (tid < 20) {
        float x2 = (e2 - mu) * rs * g_mha[512 + tid] + b_mha[512 + tid];
        y[512 + tid] = x2;
        xr[512 + tid] = __float2bfloat16(x2);
    }
    __syncthreads();

    // qkmp[row][h] = y . wq[h]   (full fp32 x, pre-rounding)
    int h = tid >> 4, sl = tid & 15;
    float acc = 0.f;
    for (int j = sl; j < D_IN; j += 16) acc += y[j] * wq[h * D_IN + j];
#pragma unroll
    for (int off = 8; off > 0; off >>= 1) acc += __shfl_down(acc, off, 16);
    if (sl == 0) qkmp[(size_t)row * NHEAD + h] = acc;
}

// ---------------- per-tree softmax over 128 members: aw[t][i][h] ----------------
__global__ void softmax_kernel(const float* __restrict__ qkmp, float* __restrict__ aw) {
    int t = blockIdx.x, tid = threadIdx.x;
    __shared__ float a[NODES_PER_TREE * NHEAD];
    for (int l = tid; l < NODES_PER_TREE * NHEAD; l += 256)
        a[l] = qkmp[(size_t)t * NODES_PER_TREE * NHEAD + l] * 0.125f;  // /sqrt(64)
    __syncthreads();

    int h = tid >> 4, sl = tid & 15;
    float m = -1e30f;
    for (int i = sl; i < NODES_PER_TREE; i += 16) m = fmaxf(m, a[i * 16 + h]);
#pragma unroll
    for (int off = 8; off > 0; off >>= 1) m = fmaxf(m, __shfl_down(m, off, 16));
    m = __shfl(m, 0, 16);
    float sum = 0.f;
    for (int i = sl; i < NODES_PER_TREE; i += 16) {
        float e = expf(a[i * 16 + h] - m);
        a[i * 16 + h] = e;
        sum += e;
    }
#pragma unroll
    for (int off = 8; off > 0; off >>= 1) sum += __shfl_down(sum, off, 16);
    sum = __shfl(sum, 0, 16);
    float inv = 1.0f / sum;
    for (int i = sl; i < NODES_PER_TREE; i += 16)
        aw[(size_t)t * NODES_PER_TREE * NHEAD + i * 16 + h] = a[i * 16 + h] * inv;
}

// ---------------- z[t][h][j] = sum_i aw[t][i][h] * xs[t*128+i][j] ----------------
// grid (4 head-groups, 128 trees); block 256
__global__ void z_kernel(const float* __restrict__ aw, const bf16* __restrict__ xs,
                         float* __restrict__ zbuf) {
    int hg = blockIdx.x, t = blockIdx.y, tid = threadIdx.x;
    __shared__ float a4[NODES_PER_TREE * 4];
    for (int l = tid; l < NODES_PER_TREE * 4; l += 256) {
        int i = l >> 2, hh = l & 3;
        a4[l] = aw[(size_t)t * NODES_PER_TREE * NHEAD + i * 16 + hg * 4 + hh];
    }
    __syncthreads();

    bool has2 = (tid + 512) < D_IN;
    float az[4][3] = {};
    const bf16* xt = xs + (size_t)t * NODES_PER_TREE * D_IN;
    for (int i = 0; i < NODES_PER_TREE; ++i) {
        const bf16* xr = xt + i * D_IN;
        float x0 = bf2f(xr[tid]);
        float x1 = bf2f(xr[tid + 256]);
        float x2 = has2 ? bf2f(xr[tid + 512]) : 0.f;
        float w0 = a4[i * 4 + 0], w1 = a4[i * 4 + 1];
        float w2 = a4[i * 4 + 2], w3 = a4[i * 4 + 3];
        az[0][0] += w0 * x0; az[0][1] += w0 * x1; az[0][2] += w0 * x2;
        az[1][0] += w1 * x0; az[1][1] += w1 * x1; az[1][2] += w1 * x2;
        az[2][0] += w2 * x0; az[2][1] += w2 * x1; az[2][2] += w2 * x2;
        az[3][0] += w3 * x0; az[3][1] += w3 * x1; az[3][2] += w3 * x2;
    }
#pragma unroll
    for (int hh = 0; hh < 4; ++hh) {
        float* zr = zbuf + (size_t)(t * NHEAD + hg * 4 + hh) * ZLD;
        zr[tid] = az[hh][0];
        zr[tid + 256] = az[hh][1];
        if (has2) zr[tid + 512] = az[hh][2];
    }
}

// ---------------- attn_out[t][c] = sum_j zbuf[t][c>>6][j] * Wv[c][j] ----------------
// grid (4 col-groups of 256, 128 trees); block 256
__global__ void contract_kernel(const float* __restrict__ zbuf, const float* __restrict__ Wv,
                                float* __restrict__ attn_out) {
    int cg = blockIdx.x, t = blockIdx.y, tid = threadIdx.x;
    __shared__ float zs[4 * ZSLD];
#pragma unroll
    for (int hh = 0; hh < 4; ++hh)
        for (int j = tid; j < D_IN; j += 256)
            zs[hh * ZSLD + j] = zbuf[(size_t)(t * NHEAD + cg * 4 + hh) * ZLD + j];
    __syncthreads();

    int grp = tid >> 4, sl = tid & 15;
#pragma unroll 2
    for (int it = 0; it < 16; ++it) {
        int lc = it * 16 + grp;            // 0..255 local col
        int c = cg * 256 + lc;
        const float* wr = Wv + (size_t)c * D_IN;
        const float* zr = zs + (lc >> 6) * ZSLD;
        float acc = 0.f;
        for (int j = sl; j < D_IN; j += 16) acc += zr[j] * wr[j];
#pragma unroll
        for (int off = 8; off > 0; off >>= 1) acc += __shfl_down(acc, off, 16);
        if (sl == 0) attn_out[(size_t)t * D_MODEL + c] = acc;
    }
}

// ---------------- split-K GEMM: Cpart[split][128,N] = A[128,K-chunk] @ B[N,K-chunk]^T ----------------
// grid (N/64, splits); block 256; per-block tile 128 rows x 64 cols, K-chunk = nsb*32
__global__ void gemm_sk_kernel(const float* __restrict__ A, const float* __restrict__ B,
                               float* __restrict__ Cpart, int N, int K, int nsb) {
    __shared__ __align__(16) float As[32 * 132];
    __shared__ __align__(16) float Bs[32 * 68];
    int tid = threadIdx.x;
    int col0 = blockIdx.x * 64;
    int k0 = blockIdx.y * nsb * 32;
    float* C = Cpart + (size_t)blockIdx.y * 128 * N;

    int ty = tid >> 4, tx = tid & 15;
    int ar = tid >> 3, akk = (tid & 7) * 4;   // A staging
    int br = tid >> 2, bkk = (tid & 3) * 8;   // B staging

    float acc[8][4] = {};

    for (int s = 0; s < nsb; ++s) {
        int kb = k0 + s * 32;
#pragma unroll
        for (int p = 0; p < 4; ++p) {
            int row = ar + p * 32;
            float4 fa = *(const float4*)(A + (size_t)row * K + kb + akk);
            As[(akk + 0) * 132 + row] = fa.x;
            As[(akk + 1) * 132 + row] = fa.y;
            As[(akk + 2) * 132 + row] = fa.z;
            As[(akk + 3) * 132 + row] = fa.w;
        }
        {
            const float* bp = B + (size_t)(col0 + br) * K + kb + bkk;
            float4 f0 = *(const float4*)(bp);
            float4 f1 = *(const float4*)(bp + 4);
            Bs[(bkk + 0) * 68 + br] = f0.x; Bs[(bkk + 1) * 68 + br] = f0.y;
            Bs[(bkk + 2) * 68 + br] = f0.z; Bs[(bkk + 3) * 68 + br] = f0.w;
            Bs[(bkk + 4) * 68 + br] = f1.x; Bs[(bkk + 5) * 68 + br] = f1.y;
            Bs[(bkk + 6) * 68 + br] = f1.z; Bs[(bkk + 7) * 68 + br] = f1.w;
        }
        __syncthreads();
#pragma unroll
        for (int k = 0; k < 32; ++k) {
            float4 a0 = *(const float4*)(As + k * 132 + ty * 8);
            float4 a1 = *(const float4*)(As + k * 132 + ty * 8 + 4);
            float4 bv = *(const float4*)(Bs + k * 68 + tx * 4);
            acc[0][0] += a0.x * bv.x; acc[0][1] += a0.x * bv.y; acc[0][2] += a0.x * bv.z; acc[0][3] += a0.x * bv.w;
            acc[1][0] += a0.y * bv.x; acc[1][1] += a0.y * bv.y; acc[1][2] += a0.y * bv.z; acc[1][3] += a0.y * bv.w;
            acc[2][0] += a0.z * bv.x; acc[2][1] += a0.z * bv.y; acc[2][2] += a0.z * bv.z; acc[2][3] += a0.z * bv.w;
            acc[3][0] += a0.w * bv.x; acc[3][1] += a0.w * bv.y; acc[3][2] += a0.w * bv.z; acc[3][3] += a0.w * bv.w;
            acc[4][0] += a1.x * bv.x; acc[4][1] += a1.x * bv.y; acc[4][2] += a1.x * bv.z; acc[4][3] += a1.x * bv.w;
            acc[5][0] += a1.y * bv.x; acc[5][1] += a1.y * bv.y; acc[5][2] += a1.y * bv.z; acc[5][3] += a1.y * bv.w;
            acc[6][0] += a1.z * bv.x; acc[6][1] += a1.z * bv.y; acc[6][2] += a1.z * bv.z; acc[6][3] += a1.z * bv.w;
            acc[7][0] += a1.w * bv.x; acc[7][1] += a1.w * bv.y; acc[7][2] += a1.w * bv.z; acc[7][3] += a1.w * bv.w;
        }
        __syncthreads();
    }
#pragma unroll
    for (int r = 0; r < 8; ++r) {
        float4 v = make_float4(acc[r][0], acc[r][1], acc[r][2], acc[r][3]);
        *(float4*)(C + (size_t)(ty * 8 + r) * N + col0 + tx * 4) = v;
    }
}

// ---------------- ln_r1: reduce 8 Wo-partials + bo + qvec -> r1; LN -> l1 ----------------
__global__ void ln_r1_kernel(const float* __restrict__ po, const float* __restrict__ bo,
                             const float* __restrict__ qvec, const float* __restrict__ g,
                             const float* __restrict__ b, float* __restrict__ r1,
                             float* __restrict__ l1) {
    int t = blockIdx.x, tid = threadIdx.x;
    __shared__ float sm[16];
    float e[4];
#pragma unroll
    for (int c = 0; c < 4; ++c) {
        int j = c * 256 + tid;
        float v = bo[j] + qvec[j];
#pragma unroll
        for (int s = 0; s < 8; ++s)
            v += po[(size_t)s * NTREE * D_MODEL + (size_t)t * D_MODEL + j];
        e[c] = v;
        r1[(size_t)t * D_MODEL + j] = v;
    }
    float s = e[0] + e[1] + e[2] + e[3];
    float ss = e[0] * e[0] + e[1] * e[1] + e[2] * e[2] + e[3] * e[3];
    blockReduceSum2(s, ss, sm);
    float mu = s * (1.f / D_MODEL);
    float var = ss * (1.f / D_MODEL) - mu * mu;
    float rs = rsqrtf(var + EPS);
#pragma unroll
    for (int c = 0; c < 4; ++c) {
        int j = c * 256 + tid;
        l1[(size_t)t * D_MODEL + j] = (e[c] - mu) * rs * g[j] + b[j];
    }
}

// ---------------- gelu_reduce: h1 = gelu(sum_8 p1 + b1) ; 128x4096 elems ----------------
__global__ void gelu_reduce_kernel(const float* __restrict__ p1, const float* __restrict__ b1,
                                   float* __restrict__ h1) {
    int idx4 = (blockIdx.x * 256 + threadIdx.x) * 4;    // < 524288
    int col = idx4 & (DFF - 1);
    float4 v = *(const float4*)(b1 + col);
#pragma unroll
    for (int s = 0; s < 8; ++s) {
        float4 p = *(const float4*)(p1 + (size_t)s * NTREE * DFF + idx4);
        v.x += p.x; v.y += p.y; v.z += p.z; v.w += p.w;
    }
    v.x = gelu_exact(v.x); v.y = gelu_exact(v.y);
    v.z = gelu_exact(v.z); v.w = gelu_exact(v.w);
    *(float4*)(h1 + idx4) = v;
}

// ---------------- ln_out: reduce 16 W2-partials + b2 + r1 -> LN -> out (+zero tail) ----------------
__global__ void ln_out_kernel(const float* __restrict__ p2, const float* __restrict__ b2,
                              const float* __restrict__ r1, const float* __restrict__ g,
                              const float* __restrict__ b, float* __restrict__ out) {
    int t = blockIdx.x, tid = threadIdx.x;
    __shared__ float sm[16];
    float e[4];
#pragma unroll
    for (int c = 0; c < 4; ++c) {
        int j = c * 256 + tid;
        float v = b2[j] + r1[(size_t)t * D_MODEL + j];
#pragma unroll
        for (int s = 0; s < 16; ++s)
            v += p2[(size_t)s * NTREE * D_MODEL + (size_t)t * D_MODEL + j];
        e[c] = v;
    }
    float s = e[0] + e[1] + e[2] + e[3];
    float ss = e[0] * e[0] + e[1] * e[1] + e[2] * e[2] + e[3] * e[3];
    blockReduceSum2(s, ss, sm);
    float mu = s * (1.f / D_MODEL);
    float var = ss * (1.f / D_MODEL) - mu * mu;
    float rs = rsqrtf(var + EPS);
#pragma unroll
    for (int c = 0; c < 4; ++c) {
        int j = c * 256 + tid;
        out[(size_t)t * D_MODEL + j] = (e[c] - mu) * rs * g[j] + b[j];
    }
    if (t == 0 && tid < 128) out[(size_t)NTREE * D_MODEL + tid] = 0.f;
}

extern "C" void kernel_launch(void* const* d_in, const int* in_sizes, int n_in,
                              void* d_out, int out_size, void* d_ws, size_t ws_size,
                              hipStream_t stream) {
    const float* values = (const float*)d_in[0];
    const int* role     = (const int*)d_in[1];
    const int* bidx     = (const int*)d_in[2];
    const int* midx     = (const int*)d_in[3];
    const float* qvec   = (const float*)d_in[4];
    const float* Wk     = (const float*)d_in[5];
    const float* Wv     = (const float*)d_in[6];
    const float* Wo     = (const float*)d_in[7];
    const float* bo     = (const float*)d_in[8];
    const float* W1     = (const float*)d_in[9];
    const float* b1     = (const float*)d_in[10];
    const float* W2     = (const float*)d_in[11];
    const float* b2     = (const float*)d_in[12];
    const float* g_fil  = (const float*)d_in[13];
    const float* b_fil  = (const float*)d_in[14];
    const float* g_mha  = (const float*)d_in[15];
    const float* b_mha  = (const float*)d_in[16];
    const float* g_ff   = (const float*)d_in[17];
    const float* b_ff   = (const float*)d_in[18];
    const float* g_out  = (const float*)d_in[19];
    const float* b_out  = (const float*)d_in[20];

    // fixed workspace region (~6.3 MB), then a big overlay region (~21.8 MB)
    char* w = (char*)d_ws;
    float* wq       = (float*)(w + 0);          // 34048 -> pad 34816
    float* qkmp     = (float*)(w + 34816);      // 1048576
    int*   counts   = (int*)  (w + 1083392);    // 512 -> pad 1024
    float* aw       = (float*)(w + 1084416);    // 1048576
    float* attn_out = (float*)(w + 2132992);    // 524288
    float* r1       = (float*)(w + 2657280);    // 524288
    float* l1       = (float*)(w + 3181568);    // 524288
    float* h1       = (float*)(w + 3705856);    // 2097152
    char*  big      = w + 5803008;              // overlay region
    // phase A (attention): zbuf + xs
    float* zbuf = (float*)big;                  // 128*16*532*4 = 4358144
    bf16*  xs   = (bf16*)(big + 4358144);       // 16384*532*2 = 17432576 -> big+21790720
    // phase B (GEMMs, after contract): partials overlay zbuf/xs
    float* po = (float*)big;                    // 8  *128*1024*4 = 4194304
    float* p1 = (float*)(big + 4194304);        // 8  *128*4096*4 = 16777216 -> big+20971520
    float* p2 = (float*)big;                    // 16 *128*1024*4 = 8388608 (po/p1 dead by then)
    // total ws use: 5803008 + 21790720 = 27593728 (~27.6 MB)

    float* out = (float*)d_out;  // [128*1024] fp32 ++ [128] pad mask zeros

    hipMemsetAsync(counts, 0, 128 * sizeof(int), stream);

    wq_kernel<<<dim3(16, 4), 256, 0, stream>>>(qvec, Wk, wq);

    node_prep_kernel<<<N_NODES, 256, 0, stream>>>(values, role, bidx, midx,
                                                  g_fil, b_fil, g_mha, b_mha,
                                                  wq, xs, qkmp, counts);

    softmax_kernel<<<NTREE, 256, 0, stream>>>(qkmp, aw);

    z_kernel<<<dim3(4, NTREE), 256, 0, stream>>>(aw, xs, zbuf);

    contract_kernel<<<dim3(4, NTREE), 256, 0, stream>>>(zbuf, Wv, attn_out);

    // Wo: K=1024, 8 splits x (4*32=128)
    gemm_sk_kernel<<<dim3(16, 8), 256, 0, stream>>>(attn_out, Wo, po, D_MODEL, D_MODEL, 4);

    ln_r1_kernel<<<NTREE, 256, 0, stream>>>(po, bo, qvec, g_ff, b_ff, r1, l1);

    // W1: K=1024, 8 splits x 128 -> p1 [8][128][4096]
    gemm_sk_kernel<<<dim3(64, 8), 256, 0, stream>>>(l1, W1, p1, DFF, D_MODEL, 4);

    gelu_reduce_kernel<<<512, 256, 0, stream>>>(p1, b1, h1);

    // W2: K=4096, 16 splits x (8*32=256) -> p2 [16][128][1024]
    gemm_sk_kernel<<<dim3(16, 16), 256, 0, stream>>>(h1, W2, p2, D_MODEL, DFF, 8);

    ln_out_kernel<<<NTREE, 256, 0, stream>>>(p2, b2, r1, g_out, b_out, out);
}

// Round 6
// 358.254 us; speedup vs baseline: 2.8456x; 1.4059x over previous
//
#include <hip/hip_runtime.h>
#include <hip/hip_bf16.h>

typedef __hip_bfloat16 bf16;

#define N_NODES 16384
#define D_FIL 512
#define D_IN 532
#define D_MODEL 1024
#define NHEAD 16
#define D_KEY 64
#define DFF 4096
#define NTREE 128
#define MEM_SLOTS 8
#define NODES_PER_TREE 128
#define EPS 1e-5f
#define ZLD 532          // zbuf row stride (fp32)

__device__ inline float bf2f(unsigned short u) {
    union { unsigned int i; float f; } v; v.i = ((unsigned int)u) << 16; return v.f;
}
__device__ inline float bf2f(bf16 x) { return __bfloat162float(x); }

__device__ inline float gelu_exact(float x) {
    return 0.5f * x * (1.0f + erff(x * 0.7071067811865476f));
}

// block-wide (256 threads) simultaneous sum of two values
__device__ inline void blockReduceSum2(float& a, float& b, float* sm) {
    int tid = threadIdx.x;
    int lane = tid & 63, wid = tid >> 6;
#pragma unroll
    for (int off = 32; off > 0; off >>= 1) {
        a += __shfl_down(a, off, 64);
        b += __shfl_down(b, off, 64);
    }
    if (lane == 0) { sm[wid] = a; sm[4 + wid] = b; }
    __syncthreads();
    if (tid == 0) {
        sm[8] = sm[0] + sm[1] + sm[2] + sm[3];
        sm[9] = sm[4] + sm[5] + sm[6] + sm[7];
    }
    __syncthreads();
    a = sm[8]; b = sm[9];
}

// ---------------- wq[h][j] = sum_d q[h][d] * Wk[h*64+d][j] ----------------
__global__ void wq_kernel(const float* __restrict__ q, const float* __restrict__ Wk,
                          float* __restrict__ wq) {
    int h = blockIdx.x, jc = blockIdx.y, tid = threadIdx.x;
    __shared__ float qs[64];
    if (tid < 64) qs[tid] = q[h * 64 + tid];
    __syncthreads();
    int jend = jc * 133 + 133;
    for (int j = jc * 133 + tid; j < jend; j += 256) {
        float acc = 0.f;
#pragma unroll 8
        for (int d = 0; d < 64; ++d)
            acc += qs[d] * Wk[(size_t)(h * 64 + d) * D_IN + j];
        wq[h * D_IN + j] = acc;
    }
}

// ---------------- wvt[j][c] = Wv[c][j]  (LDS-tiled transpose) ----------------
__global__ void transpose_wv_kernel(const float* __restrict__ Wv, float* __restrict__ wvt) {
    __shared__ float tile[32][33];
    int c0 = blockIdx.x * 32, j0 = blockIdx.y * 32;
    int tx = threadIdx.x & 31, ty = threadIdx.x >> 5;   // 32 x 8
#pragma unroll
    for (int r = 0; r < 4; ++r) {
        int cc = ty + r * 8;
        int j = j0 + tx;
        tile[cc][tx] = (j < D_IN) ? Wv[(size_t)(c0 + cc) * D_IN + j] : 0.f;
    }
    __syncthreads();
#pragma unroll
    for (int r = 0; r < 4; ++r) {
        int j = j0 + ty + r * 8;
        if (j < D_IN) wvt[(size_t)j * D_MODEL + c0 + tx] = tile[tx][ty + r * 8];
    }
}

// ------------- per-node: LN(values) ++ tpd -> LN -> xs(bf16, tree-permuted) ; qkmp -------------
__global__ void node_prep_kernel(const float* __restrict__ values, const int* __restrict__ role,
                                 const int* __restrict__ bidx, const int* __restrict__ midx,
                                 const float* __restrict__ g_fil, const float* __restrict__ b_fil,
                                 const float* __restrict__ g_mha, const float* __restrict__ b_mha,
                                 const float* __restrict__ wq,
                                 bf16* __restrict__ xs, float* __restrict__ qkmp,
                                 int* __restrict__ counts) {
    int n = blockIdx.x, tid = threadIdx.x;
    __shared__ float y[D_IN];
    __shared__ float sm[16];
    __shared__ int rowS;
    if (tid == 0) {
        int slot = bidx[n] * MEM_SLOTS + midx[n];
        int pos = atomicAdd(&counts[slot], 1);
        rowS = slot * NODES_PER_TREE + pos;
    }

    float v0 = values[(size_t)n * D_FIL + tid];
    float v1 = values[(size_t)n * D_FIL + 256 + tid];
    float s = v0 + v1, ss = v0 * v0 + v1 * v1;
    blockReduceSum2(s, ss, sm);
    float mu = s * (1.f / D_FIL);
    float var = ss * (1.f / D_FIL) - mu * mu;
    float rs = rsqrtf(var + EPS);
    y[tid] = (v0 - mu) * rs * g_fil[tid] + b_fil[tid];
    y[tid + 256] = (v1 - mu) * rs * g_fil[tid + 256] + b_fil[tid + 256];
    if (tid < 20) {
        int r = role[n];
        int cm = 31 - __clz(r);     // highest set bit (r >= 1)
        int bit = (r >> tid) & 1;
        y[512 + tid] = (tid < cm) ? (bit ? 1.f : -1.f) : 0.f;
    }
    __syncthreads();

    int row = rowS;
    float e0 = y[tid], e1 = y[tid + 256], e2 = (tid < 20) ? y[512 + tid] : 0.f;
    s = e0 + e1 + e2; ss = e0 * e0 + e1 * e1 + e2 * e2;
    blockReduceSum2(s, ss, sm);
    mu = s * (1.f / D_IN);
    var = ss * (1.f / D_IN) - mu * mu;
    rs = rsqrtf(var + EPS);
    float x0 = (e0 - mu) * rs * g_mha[tid] + b_mha[tid];
    float x1 = (e1 - mu) * rs * g_mha[tid + 256] + b_mha[tid + 256];
    y[tid] = x0; y[tid + 256] = x1;
    bf16* xr = xs + (size_t)row * D_IN;
    xr[tid] = __float2bfloat16(x0);
    xr[tid + 256] = __float2bfloat16(x1);
    if (tid < 20) {
        float x2 = (e2 - mu) * rs * g_mha[512 + tid] + b_mha[512 + tid];
        y[512 + tid] = x2;
        xr[512 + tid] = __float2bfloat16(x2);
    }
    __syncthreads();

    // qkmp[row][h] = y . wq[h]   (full fp32 x, pre-rounding)
    int h = tid >> 4, sl = tid & 15;
    float acc = 0.f;
    for (int j = sl; j < D_IN; j += 16) acc += y[j] * wq[h * D_IN + j];
#pragma unroll
    for (int off = 8; off > 0; off >>= 1) acc += __shfl_down(acc, off, 16);
    if (sl == 0) qkmp[(size_t)row * NHEAD + h] = acc;
}

// ---------------- per-tree softmax over 128 members: aw[t][i][h] ----------------
__global__ void softmax_kernel(const float* __restrict__ qkmp, float* __restrict__ aw) {
    int t = blockIdx.x, tid = threadIdx.x;
    __shared__ float a[NODES_PER_TREE * NHEAD];
    for (int l = tid; l < NODES_PER_TREE * NHEAD; l += 256)
        a[l] = qkmp[(size_t)t * NODES_PER_TREE * NHEAD + l] * 0.125f;  // /sqrt(64)
    __syncthreads();

    int h = tid >> 4, sl = tid & 15;
    float m = -1e30f;
    for (int i = sl; i < NODES_PER_TREE; i += 16) m = fmaxf(m, a[i * 16 + h]);
#pragma unroll
    for (int off = 8; off > 0; off >>= 1) m = fmaxf(m, __shfl_down(m, off, 16));
    m = __shfl(m, 0, 16);
    float sum = 0.f;
    for (int i = sl; i < NODES_PER_TREE; i += 16) {
        float e = expf(a[i * 16 + h] - m);
        a[i * 16 + h] = e;
        sum += e;
    }
#pragma unroll
    for (int off = 8; off > 0; off >>= 1) sum += __shfl_down(sum, off, 16);
    sum = __shfl(sum, 0, 16);
    float inv = 1.0f / sum;
    for (int i = sl; i < NODES_PER_TREE; i += 16)
        aw[(size_t)t * NODES_PER_TREE * NHEAD + i * 16 + h] = a[i * 16 + h] * inv;
}

// ---------------- z[t][h][j] = sum_i aw[t][i][h] * xs[t*128+i][j] ----------------
// grid (4 head-groups, 128 trees); block 256; uint loads = 2 bf16/lane
__global__ void z_kernel(const float* __restrict__ aw, const bf16* __restrict__ xs,
                         float* __restrict__ zbuf) {
    int hg = blockIdx.x, t = blockIdx.y, tid = threadIdx.x;
    __shared__ float a4[NODES_PER_TREE * 4];
    for (int l = tid; l < NODES_PER_TREE * 4; l += 256) {
        int i = l >> 2, hh = l & 3;
        a4[l] = aw[(size_t)t * NODES_PER_TREE * NHEAD + i * 16 + hg * 4 + hh];
    }
    __syncthreads();

    bool hasT = tid < 10;                     // tail uints 256..265 (j = 512..531)
    float az[4][2] = {};
    float at[4][2] = {};
    const bf16* xt = xs + (size_t)t * NODES_PER_TREE * D_IN;
    for (int i = 0; i < NODES_PER_TREE; ++i) {
        const unsigned int* xr = (const unsigned int*)(xt + i * D_IN);
        unsigned int u = xr[tid];
        unsigned int u2 = hasT ? xr[256 + tid] : 0u;
        float x0 = __uint_as_float(u << 16);
        float x1 = __uint_as_float(u & 0xffff0000u);
        float x2 = __uint_as_float(u2 << 16);
        float x3 = __uint_as_float(u2 & 0xffff0000u);
#pragma unroll
        for (int hh = 0; hh < 4; ++hh) {
            float w = a4[i * 4 + hh];
            az[hh][0] += w * x0; az[hh][1] += w * x1;
            at[hh][0] += w * x2; at[hh][1] += w * x3;
        }
    }
#pragma unroll
    for (int hh = 0; hh < 4; ++hh) {
        float* zr = zbuf + (size_t)(t * NHEAD + hg * 4 + hh) * ZLD;
        *(float2*)(zr + 2 * tid) = make_float2(az[hh][0], az[hh][1]);
        if (hasT) *(float2*)(zr + 512 + 2 * tid) = make_float2(at[hh][0], at[hh][1]);
    }
}

// ---------------- attn_out[t][c] = sum_j zbuf[t][c>>6][j] * wvt[j][c] ----------------
// grid (4 col-groups of 256, 128 trees); block 256; one col per thread
__global__ void contract_kernel(const float* __restrict__ zbuf, const float* __restrict__ wvt,
                                float* __restrict__ attn_out) {
    int cg = blockIdx.x, t = blockIdx.y, tid = threadIdx.x;
    __shared__ float zs[4][536];
#pragma unroll
    for (int hh = 0; hh < 4; ++hh)
        for (int j = tid; j < D_IN; j += 256)
            zs[hh][j] = zbuf[(size_t)(t * NHEAD + cg * 4 + hh) * ZLD + j];
    __syncthreads();

    int hh = tid >> 6;                 // wave-uniform head-within-group
    int c = cg * 256 + tid;
    const float* wp = wvt + c;
    float acc = 0.f;
#pragma unroll 4
    for (int j = 0; j < D_IN; ++j)
        acc += zs[hh][j] * wp[(size_t)j * D_MODEL];
    attn_out[(size_t)t * D_MODEL + c] = acc;
}

// ---------------- split-K GEMM: Cpart[split][128,N] = A[128,K-chunk] @ B[N,K-chunk]^T ----------------
// grid (N/64, splits); block 256; per-block tile 128 rows x 64 cols, K-chunk = nsb*32
__global__ void gemm_sk_kernel(const float* __restrict__ A, const float* __restrict__ B,
                               float* __restrict__ Cpart, int N, int K, int nsb) {
    __shared__ __align__(16) float As[32 * 132];
    __shared__ __align__(16) float Bs[32 * 68];
    int tid = threadIdx.x;
    int col0 = blockIdx.x * 64;
    int k0 = blockIdx.y * nsb * 32;
    float* C = Cpart + (size_t)blockIdx.y * 128 * N;

    int ty = tid >> 4, tx = tid & 15;
    int ar = tid >> 3, akk = (tid & 7) * 4;   // A staging
    int br = tid >> 2, bkk = (tid & 3) * 8;   // B staging

    float acc[8][4] = {};

    for (int s = 0; s < nsb; ++s) {
        int kb = k0 + s * 32;
#pragma unroll
        for (int p = 0; p < 4; ++p) {
            int row = ar + p * 32;
            float4 fa = *(const float4*)(A + (size_t)row * K + kb + akk);
            As[(akk + 0) * 132 + row] = fa.x;
            As[(akk + 1) * 132 + row] = fa.y;
            As[(akk + 2) * 132 + row] = fa.z;
            As[(akk + 3) * 132 + row] = fa.w;
        }
        {
            const float* bp = B + (size_t)(col0 + br) * K + kb + bkk;
            float4 f0 = *(const float4*)(bp);
            float4 f1 = *(const float4*)(bp + 4);
            Bs[(bkk + 0) * 68 + br] = f0.x; Bs[(bkk + 1) * 68 + br] = f0.y;
            Bs[(bkk + 2) * 68 + br] = f0.z; Bs[(bkk + 3) * 68 + br] = f0.w;
            Bs[(bkk + 4) * 68 + br] = f1.x; Bs[(bkk + 5) * 68 + br] = f1.y;
            Bs[(bkk + 6) * 68 + br] = f1.z; Bs[(bkk + 7) * 68 + br] = f1.w;
        }
        __syncthreads();
#pragma unroll
        for (int k = 0; k < 32; ++k) {
            float4 a0 = *(const float4*)(As + k * 132 + ty * 8);
            float4 a1 = *(const float4*)(As + k * 132 + ty * 8 + 4);
            float4 bv = *(const float4*)(Bs + k * 68 + tx * 4);
            acc[0][0] += a0.x * bv.x; acc[0][1] += a0.x * bv.y; acc[0][2] += a0.x * bv.z; acc[0][3] += a0.x * bv.w;
            acc[1][0] += a0.y * bv.x; acc[1][1] += a0.y * bv.y; acc[1][2] += a0.y * bv.z; acc[1][3] += a0.y * bv.w;
            acc[2][0] += a0.z * bv.x; acc[2][1] += a0.z * bv.y; acc[2][2] += a0.z * bv.z; acc[2][3] += a0.z * bv.w;
            acc[3][0] += a0.w * bv.x; acc[3][1] += a0.w * bv.y; acc[3][2] += a0.w * bv.z; acc[3][3] += a0.w * bv.w;
            acc[4][0] += a1.x * bv.x; acc[4][1] += a1.x * bv.y; acc[4][2] += a1.x * bv.z; acc[4][3] += a1.x * bv.w;
            acc[5][0] += a1.y * bv.x; acc[5][1] += a1.y * bv.y; acc[5][2] += a1.y * bv.z; acc[5][3] += a1.y * bv.w;
            acc[6][0] += a1.z * bv.x; acc[6][1] += a1.z * bv.y; acc[6][2] += a1.z * bv.z; acc[6][3] += a1.z * bv.w;
            acc[7][0] += a1.w * bv.x; acc[7][1] += a1.w * bv.y; acc[7][2] += a1.w * bv.z; acc[7][3] += a1.w * bv.w;
        }
        __syncthreads();
    }
#pragma unroll
    for (int r = 0; r < 8; ++r) {
        float4 v = make_float4(acc[r][0], acc[r][1], acc[r][2], acc[r][3]);
        *(float4*)(C + (size_t)(ty * 8 + r) * N + col0 + tx * 4) = v;
    }
}

// ---------------- ln_r1: reduce 8 Wo-partials + bo + qvec -> r1; LN -> l1 ----------------
__global__ void ln_r1_kernel(const float* __restrict__ po, const float* __restrict__ bo,
                             const float* __restrict__ qvec, const float* __restrict__ g,
                             const float* __restrict__ b, float* __restrict__ r1,
                             float* __restrict__ l1) {
    int t = blockIdx.x, tid = threadIdx.x;
    __shared__ float sm[16];
    float e[4];
#pragma unroll
    for (int c = 0; c < 4; ++c) {
        int j = c * 256 + tid;
        float v = bo[j] + qvec[j];
#pragma unroll
        for (int s = 0; s < 8; ++s)
            v += po[(size_t)s * NTREE * D_MODEL + (size_t)t * D_MODEL + j];
        e[c] = v;
        r1[(size_t)t * D_MODEL + j] = v;
    }
    float s = e[0] + e[1] + e[2] + e[3];
    float ss = e[0] * e[0] + e[1] * e[1] + e[2] * e[2] + e[3] * e[3];
    blockReduceSum2(s, ss, sm);
    float mu = s * (1.f / D_MODEL);
    float var = ss * (1.f / D_MODEL) - mu * mu;
    float rs = rsqrtf(var + EPS);
#pragma unroll
    for (int c = 0; c < 4; ++c) {
        int j = c * 256 + tid;
        l1[(size_t)t * D_MODEL + j] = (e[c] - mu) * rs * g[j] + b[j];
    }
}

// ---------------- gelu_reduce: h1 = gelu(sum_8 p1 + b1) ; 128x4096 elems ----------------
__global__ void gelu_reduce_kernel(const float* __restrict__ p1, const float* __restrict__ b1,
                                   float* __restrict__ h1) {
    int idx4 = (blockIdx.x * 256 + threadIdx.x) * 4;    // < 524288
    int col = idx4 & (DFF - 1);
    float4 v = *(const float4*)(b1 + col);
#pragma unroll
    for (int s = 0; s < 8; ++s) {
        float4 p = *(const float4*)(p1 + (size_t)s * NTREE * DFF + idx4);
        v.x += p.x; v.y += p.y; v.z += p.z; v.w += p.w;
    }
    v.x = gelu_exact(v.x); v.y = gelu_exact(v.y);
    v.z = gelu_exact(v.z); v.w = gelu_exact(v.w);
    *(float4*)(h1 + idx4) = v;
}

// ---------------- ln_out: reduce 16 W2-partials + b2 + r1 -> LN -> out (+zero tail) ----------------
__global__ void ln_out_kernel(const float* __restrict__ p2, const float* __restrict__ b2,
                              const float* __restrict__ r1, const float* __restrict__ g,
                              const float* __restrict__ b, float* __restrict__ out) {
    int t = blockIdx.x, tid = threadIdx.x;
    __shared__ float sm[16];
    float e[4];
#pragma unroll
    for (int c = 0; c < 4; ++c) {
        int j = c * 256 + tid;
        float v = b2[j] + r1[(size_t)t * D_MODEL + j];
#pragma unroll
        for (int s = 0; s < 16; ++s)
            v += p2[(size_t)s * NTREE * D_MODEL + (size_t)t * D_MODEL + j];
        e[c] = v;
    }
    float s = e[0] + e[1] + e[2] + e[3];
    float ss = e[0] * e[0] + e[1] * e[1] + e[2] * e[2] + e[3] * e[3];
    blockReduceSum2(s, ss, sm);
    float mu = s * (1.f / D_MODEL);
    float var = ss * (1.f / D_MODEL) - mu * mu;
    float rs = rsqrtf(var + EPS);
#pragma unroll
    for (int c = 0; c < 4; ++c) {
        int j = c * 256 + tid;
        out[(size_t)t * D_MODEL + j] = (e[c] - mu) * rs * g[j] + b[j];
    }
    if (t == 0 && tid < 128) out[(size_t)NTREE * D_MODEL + tid] = 0.f;
}

extern "C" void kernel_launch(void* const* d_in, const int* in_sizes, int n_in,
                              void* d_out, int out_size, void* d_ws, size_t ws_size,
                              hipStream_t stream) {
    const float* values = (const float*)d_in[0];
    const int* role     = (const int*)d_in[1];
    const int* bidx     = (const int*)d_in[2];
    const int* midx     = (const int*)d_in[3];
    const float* qvec   = (const float*)d_in[4];
    const float* Wk     = (const float*)d_in[5];
    const float* Wv     = (const float*)d_in[6];
    const float* Wo     = (const float*)d_in[7];
    const float* bo     = (const float*)d_in[8];
    const float* W1     = (const float*)d_in[9];
    const float* b1     = (const float*)d_in[10];
    const float* W2     = (const float*)d_in[11];
    const float* b2     = (const float*)d_in[12];
    const float* g_fil  = (const float*)d_in[13];
    const float* b_fil  = (const float*)d_in[14];
    const float* g_mha  = (const float*)d_in[15];
    const float* b_mha  = (const float*)d_in[16];
    const float* g_ff   = (const float*)d_in[17];
    const float* b_ff   = (const float*)d_in[18];
    const float* g_out  = (const float*)d_in[19];
    const float* b_out  = (const float*)d_in[20];

    // fixed region (~8.0 MB) + overlay region (~21.8 MB) = ~29.8 MB
    char* w = (char*)d_ws;
    float* wq       = (float*)(w + 0);          // 34048 -> pad 34816
    float* qkmp     = (float*)(w + 34816);      // 1048576
    int*   counts   = (int*)  (w + 1083392);    // 512 -> pad 1024
    float* aw       = (float*)(w + 1084416);    // 1048576
    float* attn_out = (float*)(w + 2132992);    // 524288
    float* r1       = (float*)(w + 2657280);    // 524288
    float* l1       = (float*)(w + 3181568);    // 524288
    float* h1       = (float*)(w + 3705856);    // 2097152
    float* wvt      = (float*)(w + 5803008);    // 532*1024*4 = 2179072 -> 7982080
    char*  big      = w + 7982080;              // overlay region
    // phase A (attention): zbuf + xs
    float* zbuf = (float*)big;                  // 128*16*532*4 = 4358144
    bf16*  xs   = (bf16*)(big + 4358144);       // 16384*532*2 = 17432576 -> big+21790720
    // phase B (GEMMs, after contract): partials overlay zbuf/xs
    float* po = (float*)big;                    // 8  *128*1024*4 = 4194304
    float* p1 = (float*)(big + 4194304);        // 8  *128*4096*4 = 16777216 -> big+20971520
    float* p2 = (float*)big;                    // 16 *128*1024*4 = 8388608 (po/p1 dead by then)

    float* out = (float*)d_out;  // [128*1024] fp32 ++ [128] pad mask zeros

    hipMemsetAsync(counts, 0, 128 * sizeof(int), stream);

    wq_kernel<<<dim3(16, 4), 256, 0, stream>>>(qvec, Wk, wq);

    transpose_wv_kernel<<<dim3(32, 17), 256, 0, stream>>>(Wv, wvt);

    node_prep_kernel<<<N_NODES, 256, 0, stream>>>(values, role, bidx, midx,
                                                  g_fil, b_fil, g_mha, b_mha,
                                                  wq, xs, qkmp, counts);

    softmax_kernel<<<NTREE, 256, 0, stream>>>(qkmp, aw);

    z_kernel<<<dim3(4, NTREE), 256, 0, stream>>>(aw, xs, zbuf);

    contract_kernel<<<dim3(4, NTREE), 256, 0, stream>>>(zbuf, wvt, attn_out);

    // Wo: K=1024, 8 splits x (4*32=128)
    gemm_sk_kernel<<<dim3(16, 8), 256, 0, stream>>>(attn_out, Wo, po, D_MODEL, D_MODEL, 4);

    ln_r1_kernel<<<NTREE, 256, 0, stream>>>(po, bo, qvec, g_ff, b_ff, r1, l1);

    // W1: K=1024, 8 splits x 128 -> p1 [8][128][4096]
    gemm_sk_kernel<<<dim3(64, 8), 256, 0, stream>>>(l1, W1, p1, DFF, D_MODEL, 4);

    gelu_reduce_kernel<<<512, 256, 0, stream>>>(p1, b1, h1);

    // W2: K=4096, 16 splits x (8*32=256) -> p2 [16][128][1024]
    gemm_sk_kernel<<<dim3(16, 16), 256, 0, stream>>>(h1, W2, p2, D_MODEL, DFF, 8);

    ln_out_kernel<<<NTREE, 256, 0, stream>>>(p2, b2, r1, g_out, b_out, out);
}

// Round 7
// 342.538 us; speedup vs baseline: 2.9761x; 1.0459x over previous
//
#include <hip/hip_runtime.h>
#include <hip/hip_bf16.h>

typedef __hip_bfloat16 bf16;

#define N_NODES 16384
#define D_FIL 512
#define D_IN 532
#define D_MODEL 1024
#define NHEAD 16
#define D_KEY 64
#define DFF 4096
#define NTREE 128
#define MEM_SLOTS 8
#define NODES_PER_TREE 128
#define EPS 1e-5f
#define ZLD 532          // zbuf row stride (fp32)

__device__ inline float bf2f(unsigned short u) {
    union { unsigned int i; float f; } v; v.i = ((unsigned int)u) << 16; return v.f;
}
__device__ inline float bf2f(bf16 x) { return __bfloat162float(x); }

__device__ inline float gelu_exact(float x) {
    return 0.5f * x * (1.0f + erff(x * 0.7071067811865476f));
}

// block-wide (256 threads) simultaneous sum of two values
__device__ inline void blockReduceSum2(float& a, float& b, float* sm) {
    int tid = threadIdx.x;
    int lane = tid & 63, wid = tid >> 6;
#pragma unroll
    for (int off = 32; off > 0; off >>= 1) {
        a += __shfl_down(a, off, 64);
        b += __shfl_down(b, off, 64);
    }
    if (lane == 0) { sm[wid] = a; sm[4 + wid] = b; }
    __syncthreads();
    if (tid == 0) {
        sm[8] = sm[0] + sm[1] + sm[2] + sm[3];
        sm[9] = sm[4] + sm[5] + sm[6] + sm[7];
    }
    __syncthreads();
    a = sm[8]; b = sm[9];
}

// ---------------- wq[h][j] = sum_d q[h][d] * Wk[h*64+d][j] ----------------
__global__ void wq_kernel(const float* __restrict__ q, const float* __restrict__ Wk,
                          float* __restrict__ wq) {
    int h = blockIdx.x, jc = blockIdx.y, tid = threadIdx.x;
    __shared__ float qs[64];
    if (tid < 64) qs[tid] = q[h * 64 + tid];
    __syncthreads();
    int jend = jc * 133 + 133;
    for (int j = jc * 133 + tid; j < jend; j += 256) {
        float acc = 0.f;
#pragma unroll 8
        for (int d = 0; d < 64; ++d)
            acc += qs[d] * Wk[(size_t)(h * 64 + d) * D_IN + j];
        wq[h * D_IN + j] = acc;
    }
}

// ---------------- wvt[j][c] = Wv[c][j]  (LDS-tiled transpose) ----------------
__global__ void transpose_wv_kernel(const float* __restrict__ Wv, float* __restrict__ wvt) {
    __shared__ float tile[32][33];
    int c0 = blockIdx.x * 32, j0 = blockIdx.y * 32;
    int tx = threadIdx.x & 31, ty = threadIdx.x >> 5;   // 32 x 8
#pragma unroll
    for (int r = 0; r < 4; ++r) {
        int cc = ty + r * 8;
        int j = j0 + tx;
        tile[cc][tx] = (j < D_IN) ? Wv[(size_t)(c0 + cc) * D_IN + j] : 0.f;
    }
    __syncthreads();
#pragma unroll
    for (int r = 0; r < 4; ++r) {
        int j = j0 + ty + r * 8;
        if (j < D_IN) wvt[(size_t)j * D_MODEL + c0 + tx] = tile[tx][ty + r * 8];
    }
}

// ------------- wave-per-node: LN(values) ++ tpd -> LN -> xs(bf16, tree-permuted) ; qkmp -------------
// grid 4096 x 256: 4 waves/block, 1 node/wave. No LDS, no barriers.
__global__ __launch_bounds__(256) void node_prep_kernel(
        const float* __restrict__ values, const int* __restrict__ role,
        const int* __restrict__ bidx, const int* __restrict__ midx,
        const float* __restrict__ g_fil, const float* __restrict__ b_fil,
        const float* __restrict__ g_mha, const float* __restrict__ b_mha,
        const float* __restrict__ wq,
        bf16* __restrict__ xs, float* __restrict__ qkmp,
        int* __restrict__ counts) {
    int wave = threadIdx.x >> 6;
    int l = threadIdx.x & 63;
    int n = blockIdx.x * 4 + wave;

    int row = 0;
    if (l == 0) {
        int slot = bidx[n] * MEM_SLOTS + midx[n];
        int pos = atomicAdd(&counts[slot], 1);
        row = slot * NODES_PER_TREE + pos;
    }
    row = __shfl(row, 0, 64);

    // ---- LN1 over 512 ----
    const float4* vp = (const float4*)(values + (size_t)n * D_FIL + l * 8);
    float4 v0 = vp[0], v1 = vp[1];
    float s = v0.x + v0.y + v0.z + v0.w + v1.x + v1.y + v1.z + v1.w;
    float ss = v0.x * v0.x + v0.y * v0.y + v0.z * v0.z + v0.w * v0.w
             + v1.x * v1.x + v1.y * v1.y + v1.z * v1.z + v1.w * v1.w;
#pragma unroll
    for (int m = 1; m < 64; m <<= 1) {
        s += __shfl_xor(s, m, 64);
        ss += __shfl_xor(ss, m, 64);
    }
    float mu = s * (1.f / D_FIL);
    float var = ss * (1.f / D_FIL) - mu * mu;
    float rs = rsqrtf(var + EPS);

    const float4* gf = (const float4*)(g_fil + l * 8);
    const float4* bf = (const float4*)(b_fil + l * 8);
    float4 gf0 = gf[0], gf1 = gf[1], bf0 = bf[0], bf1 = bf[1];
    float y[8];
    y[0] = (v0.x - mu) * rs * gf0.x + bf0.x;
    y[1] = (v0.y - mu) * rs * gf0.y + bf0.y;
    y[2] = (v0.z - mu) * rs * gf0.z + bf0.z;
    y[3] = (v0.w - mu) * rs * gf0.w + bf0.w;
    y[4] = (v1.x - mu) * rs * gf1.x + bf1.x;
    y[5] = (v1.y - mu) * rs * gf1.y + bf1.y;
    y[6] = (v1.z - mu) * rs * gf1.z + bf1.z;
    y[7] = (v1.w - mu) * rs * gf1.w + bf1.w;

    // ---- tpd analytic stats ----
    int r = role[n];                 // r >= 1
    int cm = 31 - __clz(r);          // highest set bit, 0..19
    float s_t = 2.f * (float)(__popc(r) - 1) - (float)cm;
    float ss_t = (float)cm;

    // ---- LN2 over 532 ----
    float s2 = y[0] + y[1] + y[2] + y[3] + y[4] + y[5] + y[6] + y[7];
    float ss2 = y[0] * y[0] + y[1] * y[1] + y[2] * y[2] + y[3] * y[3]
              + y[4] * y[4] + y[5] * y[5] + y[6] * y[6] + y[7] * y[7];
#pragma unroll
    for (int m = 1; m < 64; m <<= 1) {
        s2 += __shfl_xor(s2, m, 64);
        ss2 += __shfl_xor(ss2, m, 64);
    }
    s2 += s_t; ss2 += ss_t;
    float mu2 = s2 * (1.f / D_IN);
    float var2 = ss2 * (1.f / D_IN) - mu2 * mu2;
    float rs2 = rsqrtf(var2 + EPS);

    const float4* gm = (const float4*)(g_mha + l * 8);
    const float4* bm = (const float4*)(b_mha + l * 8);
    float4 gm0 = gm[0], gm1 = gm[1], bm0 = bm[0], bm1 = bm[1];
    float x[8];
    x[0] = (y[0] - mu2) * rs2 * gm0.x + bm0.x;
    x[1] = (y[1] - mu2) * rs2 * gm0.y + bm0.y;
    x[2] = (y[2] - mu2) * rs2 * gm0.z + bm0.z;
    x[3] = (y[3] - mu2) * rs2 * gm0.w + bm0.w;
    x[4] = (y[4] - mu2) * rs2 * gm1.x + bm1.x;
    x[5] = (y[5] - mu2) * rs2 * gm1.y + bm1.y;
    x[6] = (y[6] - mu2) * rs2 * gm1.z + bm1.z;
    x[7] = (y[7] - mu2) * rs2 * gm1.w + bm1.w;

    // store 8 bf16 (two 8B stores; row base only 8B-aligned)
    {
        unsigned short us[8];
#pragma unroll
        for (int k = 0; k < 8; ++k)
            us[k] = (unsigned short)(__bfloat16_as_ushort(__float2bfloat16(x[k])));
        uint2 lo = make_uint2(((unsigned)us[1] << 16) | us[0], ((unsigned)us[3] << 16) | us[2]);
        uint2 hi = make_uint2(((unsigned)us[5] << 16) | us[4], ((unsigned)us[7] << 16) | us[6]);
        char* base = (char*)(xs + (size_t)row * D_IN + l * 8);
        *(uint2*)base = lo;
        *(uint2*)(base + 8) = hi;
    }

    // tail j = 512..531
    float x2 = 0.f;
    if (l < 20) {
        int bit = (r >> l) & 1;
        float tpd = (l < cm) ? (bit ? 1.f : -1.f) : 0.f;
        x2 = (tpd - mu2) * rs2 * g_mha[512 + l] + b_mha[512 + l];
        xs[(size_t)row * D_IN + 512 + l] = __float2bfloat16(x2);
    }

    // ---- qkm over 16 heads, register-resident ----
    float acc[NHEAD];
#pragma unroll
    for (int h = 0; h < NHEAD; ++h) {
        const float4* wp = (const float4*)(wq + h * D_IN + l * 8);
        float4 w0 = wp[0], w1 = wp[1];
        float a = x[0] * w0.x + x[1] * w0.y + x[2] * w0.z + x[3] * w0.w
                + x[4] * w1.x + x[5] * w1.y + x[6] * w1.z + x[7] * w1.w;
        if (l < 20) a += x2 * wq[h * D_IN + 512 + l];
        acc[h] = a;
    }
#pragma unroll
    for (int h = 0; h < NHEAD; ++h) {
#pragma unroll
        for (int off = 32; off > 0; off >>= 1)
            acc[h] += __shfl_down(acc[h], off, 64);
    }
    if (l == 0) {
        float* qr = qkmp + (size_t)row * NHEAD;
#pragma unroll
        for (int h = 0; h < NHEAD; ++h) qr[h] = acc[h];
    }
}

// ---------------- per-tree softmax over 128 members: aw[t][i][h] ----------------
__global__ void softmax_kernel(const float* __restrict__ qkmp, float* __restrict__ aw) {
    int t = blockIdx.x, tid = threadIdx.x;
    __shared__ float a[NODES_PER_TREE * NHEAD];
    for (int l = tid; l < NODES_PER_TREE * NHEAD; l += 256)
        a[l] = qkmp[(size_t)t * NODES_PER_TREE * NHEAD + l] * 0.125f;  // /sqrt(64)
    __syncthreads();

    int h = tid >> 4, sl = tid & 15;
    float m = -1e30f;
    for (int i = sl; i < NODES_PER_TREE; i += 16) m = fmaxf(m, a[i * 16 + h]);
#pragma unroll
    for (int off = 8; off > 0; off >>= 1) m = fmaxf(m, __shfl_down(m, off, 16));
    m = __shfl(m, 0, 16);
    float sum = 0.f;
    for (int i = sl; i < NODES_PER_TREE; i += 16) {
        float e = expf(a[i * 16 + h] - m);
        a[i * 16 + h] = e;
        sum += e;
    }
#pragma unroll
    for (int off = 8; off > 0; off >>= 1) sum += __shfl_down(sum, off, 16);
    sum = __shfl(sum, 0, 16);
    float inv = 1.0f / sum;
    for (int i = sl; i < NODES_PER_TREE; i += 16)
        aw[(size_t)t * NODES_PER_TREE * NHEAD + i * 16 + h] = a[i * 16 + h] * inv;
}

// ---------------- z[t][h][j] = sum_i aw[t][i][h] * xs[t*128+i][j] ----------------
// grid (4 head-groups, 128 trees); block 256; uint loads = 2 bf16/lane
__global__ void z_kernel(const float* __restrict__ aw, const bf16* __restrict__ xs,
                         float* __restrict__ zbuf) {
    int hg = blockIdx.x, t = blockIdx.y, tid = threadIdx.x;
    __shared__ float a4[NODES_PER_TREE * 4];
    for (int l = tid; l < NODES_PER_TREE * 4; l += 256) {
        int i = l >> 2, hh = l & 3;
        a4[l] = aw[(size_t)t * NODES_PER_TREE * NHEAD + i * 16 + hg * 4 + hh];
    }
    __syncthreads();

    bool hasT = tid < 10;                     // tail uints 256..265 (j = 512..531)
    float az[4][2] = {};
    float at[4][2] = {};
    const bf16* xt = xs + (size_t)t * NODES_PER_TREE * D_IN;
    for (int i = 0; i < NODES_PER_TREE; ++i) {
        const unsigned int* xr = (const unsigned int*)(xt + i * D_IN);
        unsigned int u = xr[tid];
        unsigned int u2 = hasT ? xr[256 + tid] : 0u;
        float x0 = __uint_as_float(u << 16);
        float x1 = __uint_as_float(u & 0xffff0000u);
        float x2 = __uint_as_float(u2 << 16);
        float x3 = __uint_as_float(u2 & 0xffff0000u);
#pragma unroll
        for (int hh = 0; hh < 4; ++hh) {
            float w = a4[i * 4 + hh];
            az[hh][0] += w * x0; az[hh][1] += w * x1;
            at[hh][0] += w * x2; at[hh][1] += w * x3;
        }
    }
#pragma unroll
    for (int hh = 0; hh < 4; ++hh) {
        float* zr = zbuf + (size_t)(t * NHEAD + hg * 4 + hh) * ZLD;
        *(float2*)(zr + 2 * tid) = make_float2(az[hh][0], az[hh][1]);
        if (hasT) *(float2*)(zr + 512 + 2 * tid) = make_float2(at[hh][0], at[hh][1]);
    }
}

// ---------------- attn_out[t][c] = sum_j zbuf[t][c>>6][j] * wvt[j][c] ----------------
// grid (4 col-groups of 256, 128 trees); block 256; one col per thread
__global__ void contract_kernel(const float* __restrict__ zbuf, const float* __restrict__ wvt,
                                float* __restrict__ attn_out) {
    int cg = blockIdx.x, t = blockIdx.y, tid = threadIdx.x;
    __shared__ float zs[4][536];
#pragma unroll
    for (int hh = 0; hh < 4; ++hh)
        for (int j = tid; j < D_IN; j += 256)
            zs[hh][j] = zbuf[(size_t)(t * NHEAD + cg * 4 + hh) * ZLD + j];
    __syncthreads();

    int hh = tid >> 6;                 // wave-uniform head-within-group
    int c = cg * 256 + tid;
    const float* wp = wvt + c;
    float acc = 0.f;
#pragma unroll 4
    for (int j = 0; j < D_IN; ++j)
        acc += zs[hh][j] * wp[(size_t)j * D_MODEL];
    attn_out[(size_t)t * D_MODEL + c] = acc;
}

// ---------------- split-K GEMM: Cpart[split][128,N] = A[128,K-chunk] @ B[N,K-chunk]^T ----------------
// grid (N/64, splits); block 256; per-block tile 128 rows x 64 cols, K-chunk = nsb*32
__global__ void gemm_sk_kernel(const float* __restrict__ A, const float* __restrict__ B,
                               float* __restrict__ Cpart, int N, int K, int nsb) {
    __shared__ __align__(16) float As[32 * 132];
    __shared__ __align__(16) float Bs[32 * 68];
    int tid = threadIdx.x;
    int col0 = blockIdx.x * 64;
    int k0 = blockIdx.y * nsb * 32;
    float* C = Cpart + (size_t)blockIdx.y * 128 * N;

    int ty = tid >> 4, tx = tid & 15;
    int ar = tid >> 3, akk = (tid & 7) * 4;   // A staging
    int br = tid >> 2, bkk = (tid & 3) * 8;   // B staging

    float acc[8][4] = {};

    for (int s = 0; s < nsb; ++s) {
        int kb = k0 + s * 32;
#pragma unroll
        for (int p = 0; p < 4; ++p) {
            int row = ar + p * 32;
            float4 fa = *(const float4*)(A + (size_t)row * K + kb + akk);
            As[(akk + 0) * 132 + row] = fa.x;
            As[(akk + 1) * 132 + row] = fa.y;
            As[(akk + 2) * 132 + row] = fa.z;
            As[(akk + 3) * 132 + row] = fa.w;
        }
        {
            const float* bp = B + (size_t)(col0 + br) * K + kb + bkk;
            float4 f0 = *(const float4*)(bp);
            float4 f1 = *(const float4*)(bp + 4);
            Bs[(bkk + 0) * 68 + br] = f0.x; Bs[(bkk + 1) * 68 + br] = f0.y;
            Bs[(bkk + 2) * 68 + br] = f0.z; Bs[(bkk + 3) * 68 + br] = f0.w;
            Bs[(bkk + 4) * 68 + br] = f1.x; Bs[(bkk + 5) * 68 + br] = f1.y;
            Bs[(bkk + 6) * 68 + br] = f1.z; Bs[(bkk + 7) * 68 + br] = f1.w;
        }
        __syncthreads();
#pragma unroll
        for (int k = 0; k < 32; ++k) {
            float4 a0 = *(const float4*)(As + k * 132 + ty * 8);
            float4 a1 = *(const float4*)(As + k * 132 + ty * 8 + 4);
            float4 bv = *(const float4*)(Bs + k * 68 + tx * 4);
            acc[0][0] += a0.x * bv.x; acc[0][1] += a0.x * bv.y; acc[0][2] += a0.x * bv.z; acc[0][3] += a0.x * bv.w;
            acc[1][0] += a0.y * bv.x; acc[1][1] += a0.y * bv.y; acc[1][2] += a0.y * bv.z; acc[1][3] += a0.y * bv.w;
            acc[2][0] += a0.z * bv.x; acc[2][1] += a0.z * bv.y; acc[2][2] += a0.z * bv.z; acc[2][3] += a0.z * bv.w;
            acc[3][0] += a0.w * bv.x; acc[3][1] += a0.w * bv.y; acc[3][2] += a0.w * bv.z; acc[3][3] += a0.w * bv.w;
            acc[4][0] += a1.x * bv.x; acc[4][1] += a1.x * bv.y; acc[4][2] += a1.x * bv.z; acc[4][3] += a1.x * bv.w;
            acc[5][0] += a1.y * bv.x; acc[5][1] += a1.y * bv.y; acc[5][2] += a1.y * bv.z; acc[5][3] += a1.y * bv.w;
            acc[6][0] += a1.z * bv.x; acc[6][1] += a1.z * bv.y; acc[6][2] += a1.z * bv.z; acc[6][3] += a1.z * bv.w;
            acc[7][0] += a1.w * bv.x; acc[7][1] += a1.w * bv.y; acc[7][2] += a1.w * bv.z; acc[7][3] += a1.w * bv.w;
        }
        __syncthreads();
    }
#pragma unroll
    for (int r = 0; r < 8; ++r) {
        float4 v = make_float4(acc[r][0], acc[r][1], acc[r][2], acc[r][3]);
        *(float4*)(C + (size_t)(ty * 8 + r) * N + col0 + tx * 4) = v;
    }
}

// ---------------- ln_r1: reduce 8 Wo-partials + bo + qvec -> r1; LN -> l1 ----------------
__global__ void ln_r1_kernel(const float* __restrict__ po, const float* __restrict__ bo,
                             const float* __restrict__ qvec, const float* __restrict__ g,
                             const float* __restrict__ b, float* __restrict__ r1,
                             float* __restrict__ l1) {
    int t = blockIdx.x, tid = threadIdx.x;
    __shared__ float sm[16];
    float e[4];
#pragma unroll
    for (int c = 0; c < 4; ++c) {
        int j = c * 256 + tid;
        float v = bo[j] + qvec[j];
#pragma unroll
        for (int s = 0; s < 8; ++s)
            v += po[(size_t)s * NTREE * D_MODEL + (size_t)t * D_MODEL + j];
        e[c] = v;
        r1[(size_t)t * D_MODEL + j] = v;
    }
    float s = e[0] + e[1] + e[2] + e[3];
    float ss = e[0] * e[0] + e[1] * e[1] + e[2] * e[2] + e[3] * e[3];
    blockReduceSum2(s, ss, sm);
    float mu = s * (1.f / D_MODEL);
    float var = ss * (1.f / D_MODEL) - mu * mu;
    float rs = rsqrtf(var + EPS);
#pragma unroll
    for (int c = 0; c < 4; ++c) {
        int j = c * 256 + tid;
        l1[(size_t)t * D_MODEL + j] = (e[c] - mu) * rs * g[j] + b[j];
    }
}

// ---------------- gelu_reduce: h1 = gelu(sum_8 p1 + b1) ; 128x4096 elems ----------------
__global__ void gelu_reduce_kernel(const float* __restrict__ p1, const float* __restrict__ b1,
                                   float* __restrict__ h1) {
    int idx4 = (blockIdx.x * 256 + threadIdx.x) * 4;    // < 524288
    int col = idx4 & (DFF - 1);
    float4 v = *(const float4*)(b1 + col);
#pragma unroll
    for (int s = 0; s < 8; ++s) {
        float4 p = *(const float4*)(p1 + (size_t)s * NTREE * DFF + idx4);
        v.x += p.x; v.y += p.y; v.z += p.z; v.w += p.w;
    }
    v.x = gelu_exact(v.x); v.y = gelu_exact(v.y);
    v.z = gelu_exact(v.z); v.w = gelu_exact(v.w);
    *(float4*)(h1 + idx4) = v;
}

// ---------------- ln_out: reduce 16 W2-partials + b2 + r1 -> LN -> out (+zero tail) ----------------
__global__ void ln_out_kernel(const float* __restrict__ p2, const float* __restrict__ b2,
                              const float* __restrict__ r1, const float* __restrict__ g,
                              const float* __restrict__ b, float* __restrict__ out) {
    int t = blockIdx.x, tid = threadIdx.x;
    __shared__ float sm[16];
    float e[4];
#pragma unroll
    for (int c = 0; c < 4; ++c) {
        int j = c * 256 + tid;
        float v = b2[j] + r1[(size_t)t * D_MODEL + j];
#pragma unroll
        for (int s = 0; s < 16; ++s)
            v += p2[(size_t)s * NTREE * D_MODEL + (size_t)t * D_MODEL + j];
        e[c] = v;
    }
    float s = e[0] + e[1] + e[2] + e[3];
    float ss = e[0] * e[0] + e[1] * e[1] + e[2] * e[2] + e[3] * e[3];
    blockReduceSum2(s, ss, sm);
    float mu = s * (1.f / D_MODEL);
    float var = ss * (1.f / D_MODEL) - mu * mu;
    float rs = rsqrtf(var + EPS);
#pragma unroll
    for (int c = 0; c < 4; ++c) {
        int j = c * 256 + tid;
        out[(size_t)t * D_MODEL + j] = (e[c] - mu) * rs * g[j] + b[j];
    }
    if (t == 0 && tid < 128) out[(size_t)NTREE * D_MODEL + tid] = 0.f;
}

extern "C" void kernel_launch(void* const* d_in, const int* in_sizes, int n_in,
                              void* d_out, int out_size, void* d_ws, size_t ws_size,
                              hipStream_t stream) {
    const float* values = (const float*)d_in[0];
    const int* role     = (const int*)d_in[1];
    const int* bidx     = (const int*)d_in[2];
    const int* midx     = (const int*)d_in[3];
    const float* qvec   = (const float*)d_in[4];
    const float* Wk     = (const float*)d_in[5];
    const float* Wv     = (const float*)d_in[6];
    const float* Wo     = (const float*)d_in[7];
    const float* bo     = (const float*)d_in[8];
    const float* W1     = (const float*)d_in[9];
    const float* b1     = (const float*)d_in[10];
    const float* W2     = (const float*)d_in[11];
    const float* b2     = (const float*)d_in[12];
    const float* g_fil  = (const float*)d_in[13];
    const float* b_fil  = (const float*)d_in[14];
    const float* g_mha  = (const float*)d_in[15];
    const float* b_mha  = (const float*)d_in[16];
    const float* g_ff   = (const float*)d_in[17];
    const float* b_ff   = (const float*)d_in[18];
    const float* g_out  = (const float*)d_in[19];
    const float* b_out  = (const float*)d_in[20];

    // fixed region (~8.0 MB) + overlay region (~21.8 MB) = ~29.8 MB
    char* w = (char*)d_ws;
    float* wq       = (float*)(w + 0);          // 34048 -> pad 34816
    float* qkmp     = (float*)(w + 34816);      // 1048576
    int*   counts   = (int*)  (w + 1083392);    // 512 -> pad 1024
    float* aw       = (float*)(w + 1084416);    // 1048576
    float* attn_out = (float*)(w + 2132992);    // 524288
    float* r1       = (float*)(w + 2657280);    // 524288
    float* l1       = (float*)(w + 3181568);    // 524288
    float* h1       = (float*)(w + 3705856);    // 2097152
    float* wvt      = (float*)(w + 5803008);    // 532*1024*4 = 2179072 -> 7982080
    char*  big      = w + 7982080;              // overlay region
    // phase A (attention): zbuf + xs
    float* zbuf = (float*)big;                  // 128*16*532*4 = 4358144
    bf16*  xs   = (bf16*)(big + 4358144);       // 16384*532*2 = 17432576 -> big+21790720
    // phase B (GEMMs, after contract): partials overlay zbuf/xs
    float* po = (float*)big;                    // 8  *128*1024*4 = 4194304
    float* p1 = (float*)(big + 4194304);        // 8  *128*4096*4 = 16777216 -> big+20971520
    float* p2 = (float*)big;                    // 16 *128*1024*4 = 8388608 (po/p1 dead by then)

    float* out = (float*)d_out;  // [128*1024] fp32 ++ [128] pad mask zeros

    hipMemsetAsync(counts, 0, 128 * sizeof(int), stream);

    wq_kernel<<<dim3(16, 4), 256, 0, stream>>>(qvec, Wk, wq);

    transpose_wv_kernel<<<dim3(32, 17), 256, 0, stream>>>(Wv, wvt);

    node_prep_kernel<<<N_NODES / 4, 256, 0, stream>>>(values, role, bidx, midx,
                                                      g_fil, b_fil, g_mha, b_mha,
                                                      wq, xs, qkmp, counts);

    softmax_kernel<<<NTREE, 256, 0, stream>>>(qkmp, aw);

    z_kernel<<<dim3(4, NTREE), 256, 0, stream>>>(aw, xs, zbuf);

    contract_kernel<<<dim3(4, NTREE), 256, 0, stream>>>(zbuf, wvt, attn_out);

    // Wo: K=1024, 8 splits x (4*32=128)
    gemm_sk_kernel<<<dim3(16, 8), 256, 0, stream>>>(attn_out, Wo, po, D_MODEL, D_MODEL, 4);

    ln_r1_kernel<<<NTREE, 256, 0, stream>>>(po, bo, qvec, g_ff, b_ff, r1, l1);

    // W1: K=1024, 8 splits x 128 -> p1 [8][128][4096]
    gemm_sk_kernel<<<dim3(64, 8), 256, 0, stream>>>(l1, W1, p1, DFF, D_MODEL, 4);

    gelu_reduce_kernel<<<512, 256, 0, stream>>>(p1, b1, h1);

    // W2: K=4096, 16 splits x (8*32=256) -> p2 [16][128][1024]
    gemm_sk_kernel<<<dim3(16, 16), 256, 0, stream>>>(h1, W2, p2, D_MODEL, DFF, 8);

    ln_out_kernel<<<NTREE, 256, 0, stream>>>(p2, b2, r1, g_out, b_out, out);
}

// Round 8
// 329.594 us; speedup vs baseline: 3.0930x; 1.0393x over previous
//
#include <hip/hip_runtime.h>
#include <hip/hip_bf16.h>

typedef __hip_bfloat16 bf16;

#define N_NODES 16384
#define D_FIL 512
#define D_IN 532
#define D_MODEL 1024
#define NHEAD 16
#define D_KEY 64
#define DFF 4096
#define NTREE 128
#define MEM_SLOTS 8
#define NODES_PER_TREE 128
#define EPS 1e-5f

__device__ inline float bf2f(unsigned short u) {
    union { unsigned int i; float f; } v; v.i = ((unsigned int)u) << 16; return v.f;
}
__device__ inline float bf2f(bf16 x) { return __bfloat162float(x); }

__device__ inline float gelu_exact(float x) {
    return 0.5f * x * (1.0f + erff(x * 0.7071067811865476f));
}

// block-wide (256 threads) simultaneous sum of two values
__device__ inline void blockReduceSum2(float& a, float& b, float* sm) {
    int tid = threadIdx.x;
    int lane = tid & 63, wid = tid >> 6;
#pragma unroll
    for (int off = 32; off > 0; off >>= 1) {
        a += __shfl_down(a, off, 64);
        b += __shfl_down(b, off, 64);
    }
    if (lane == 0) { sm[wid] = a; sm[4 + wid] = b; }
    __syncthreads();
    if (tid == 0) {
        sm[8] = sm[0] + sm[1] + sm[2] + sm[3];
        sm[9] = sm[4] + sm[5] + sm[6] + sm[7];
    }
    __syncthreads();
    a = sm[8]; b = sm[9];
}

// ---------------- wq[h][j] = sum_d q[h][d] * Wk[h*64+d][j]; also bf16-packed wqb ----------------
__global__ void wq_kernel(const float* __restrict__ q, const float* __restrict__ Wk,
                          float* __restrict__ wq, bf16* __restrict__ wqb) {
    int h = blockIdx.x, jc = blockIdx.y, tid = threadIdx.x;
    __shared__ float qs[64];
    if (tid < 64) qs[tid] = q[h * 64 + tid];
    __syncthreads();
    int jend = jc * 133 + 133;
    for (int j = jc * 133 + tid; j < jend; j += 256) {
        float acc = 0.f;
#pragma unroll 8
        for (int d = 0; d < 64; ++d)
            acc += qs[d] * Wk[(size_t)(h * 64 + d) * D_IN + j];
        wq[h * D_IN + j] = acc;
        if (j < 512) wqb[h * 512 + j] = __float2bfloat16(acc);
    }
}

// ---------------- wvt[j][c] = Wv[c][j]  (LDS-tiled transpose) ----------------
__global__ void transpose_wv_kernel(const float* __restrict__ Wv, float* __restrict__ wvt) {
    __shared__ float tile[32][33];
    int c0 = blockIdx.x * 32, j0 = blockIdx.y * 32;
    int tx = threadIdx.x & 31, ty = threadIdx.x >> 5;   // 32 x 8
#pragma unroll
    for (int r = 0; r < 4; ++r) {
        int cc = ty + r * 8;
        int j = j0 + tx;
        tile[cc][tx] = (j < D_IN) ? Wv[(size_t)(c0 + cc) * D_IN + j] : 0.f;
    }
    __syncthreads();
#pragma unroll
    for (int r = 0; r < 4; ++r) {
        int j = j0 + ty + r * 8;
        if (j < D_IN) wvt[(size_t)j * D_MODEL + c0 + tx] = tile[tx][ty + r * 8];
    }
}

// ------------- wave-per-node: LN(values) ++ tpd -> LN -> xs(bf16, tree-permuted) ; qkmp -------------
// grid 4096 x 256: 4 waves/block, 1 node/wave. No LDS, no barriers.
// launch_bounds(256,4): allow up to 128 VGPRs so the 16 wqb loads stay in flight.
__global__ __launch_bounds__(256, 4) void node_prep_kernel(
        const float* __restrict__ values, const int* __restrict__ role,
        const int* __restrict__ bidx, const int* __restrict__ midx,
        const float* __restrict__ g_fil, const float* __restrict__ b_fil,
        const float* __restrict__ g_mha, const float* __restrict__ b_mha,
        const float* __restrict__ wq, const bf16* __restrict__ wqb,
        bf16* __restrict__ xs, float* __restrict__ qkmp,
        int* __restrict__ counts) {
    int wave = threadIdx.x >> 6;
    int l = threadIdx.x & 63;
    int n = blockIdx.x * 4 + wave;

    int row = 0;
    if (l == 0) {
        int slot = bidx[n] * MEM_SLOTS + midx[n];
        int pos = atomicAdd(&counts[slot], 1);
        row = slot * NODES_PER_TREE + pos;
    }
    row = __shfl(row, 0, 64);

    // ---- LN1 over 512 ----
    const float4* vp = (const float4*)(values + (size_t)n * D_FIL + l * 8);
    float4 v0 = vp[0], v1 = vp[1];
    float s = v0.x + v0.y + v0.z + v0.w + v1.x + v1.y + v1.z + v1.w;
    float ss = v0.x * v0.x + v0.y * v0.y + v0.z * v0.z + v0.w * v0.w
             + v1.x * v1.x + v1.y * v1.y + v1.z * v1.z + v1.w * v1.w;
#pragma unroll
    for (int m = 1; m < 64; m <<= 1) {
        s += __shfl_xor(s, m, 64);
        ss += __shfl_xor(ss, m, 64);
    }
    float mu = s * (1.f / D_FIL);
    float var = ss * (1.f / D_FIL) - mu * mu;
    float rs = rsqrtf(var + EPS);

    const float4* gf = (const float4*)(g_fil + l * 8);
    const float4* bf = (const float4*)(b_fil + l * 8);
    float4 gf0 = gf[0], gf1 = gf[1], bf0 = bf[0], bf1 = bf[1];
    float y[8];
    y[0] = (v0.x - mu) * rs * gf0.x + bf0.x;
    y[1] = (v0.y - mu) * rs * gf0.y + bf0.y;
    y[2] = (v0.z - mu) * rs * gf0.z + bf0.z;
    y[3] = (v0.w - mu) * rs * gf0.w + bf0.w;
    y[4] = (v1.x - mu) * rs * gf1.x + bf1.x;
    y[5] = (v1.y - mu) * rs * gf1.y + bf1.y;
    y[6] = (v1.z - mu) * rs * gf1.z + bf1.z;
    y[7] = (v1.w - mu) * rs * gf1.w + bf1.w;

    // ---- tpd analytic stats ----
    int r = role[n];                 // r >= 1
    int cm = 31 - __clz(r);          // highest set bit, 0..19
    float s_t = 2.f * (float)(__popc(r) - 1) - (float)cm;
    float ss_t = (float)cm;

    // ---- LN2 over 532 ----
    float s2 = y[0] + y[1] + y[2] + y[3] + y[4] + y[5] + y[6] + y[7];
    float ss2 = y[0] * y[0] + y[1] * y[1] + y[2] * y[2] + y[3] * y[3]
              + y[4] * y[4] + y[5] * y[5] + y[6] * y[6] + y[7] * y[7];
#pragma unroll
    for (int m = 1; m < 64; m <<= 1) {
        s2 += __shfl_xor(s2, m, 64);
        ss2 += __shfl_xor(ss2, m, 64);
    }
    s2 += s_t; ss2 += ss_t;
    float mu2 = s2 * (1.f / D_IN);
    float var2 = ss2 * (1.f / D_IN) - mu2 * mu2;
    float rs2 = rsqrtf(var2 + EPS);

    const float4* gm = (const float4*)(g_mha + l * 8);
    const float4* bm = (const float4*)(b_mha + l * 8);
    float4 gm0 = gm[0], gm1 = gm[1], bm0 = bm[0], bm1 = bm[1];
    float x[8];
    x[0] = (y[0] - mu2) * rs2 * gm0.x + bm0.x;
    x[1] = (y[1] - mu2) * rs2 * gm0.y + bm0.y;
    x[2] = (y[2] - mu2) * rs2 * gm0.z + bm0.z;
    x[3] = (y[3] - mu2) * rs2 * gm0.w + bm0.w;
    x[4] = (y[4] - mu2) * rs2 * gm1.x + bm1.x;
    x[5] = (y[5] - mu2) * rs2 * gm1.y + bm1.y;
    x[6] = (y[6] - mu2) * rs2 * gm1.z + bm1.z;
    x[7] = (y[7] - mu2) * rs2 * gm1.w + bm1.w;

    // store 8 bf16 (two 8B stores; row base only 8B-aligned)
    {
        unsigned short us[8];
#pragma unroll
        for (int k = 0; k < 8; ++k)
            us[k] = (unsigned short)(__bfloat16_as_ushort(__float2bfloat16(x[k])));
        uint2 lo = make_uint2(((unsigned)us[1] << 16) | us[0], ((unsigned)us[3] << 16) | us[2]);
        uint2 hi = make_uint2(((unsigned)us[5] << 16) | us[4], ((unsigned)us[7] << 16) | us[6]);
        char* base = (char*)(xs + (size_t)row * D_IN + l * 8);
        *(uint2*)base = lo;
        *(uint2*)(base + 8) = hi;
    }

    // tail j = 512..531
    float x2 = 0.f;
    if (l < 20) {
        int bit = (r >> l) & 1;
        float tpd = (l < cm) ? (bit ? 1.f : -1.f) : 0.f;
        x2 = (tpd - mu2) * rs2 * g_mha[512 + l] + b_mha[512 + l];
        xs[(size_t)row * D_IN + 512 + l] = __float2bfloat16(x2);
    }

    // ---- qkm over 16 heads: one uint4 (8 bf16 weights) per head per lane ----
    const uint4* wb = (const uint4*)wqb;   // head row = 64 uint4
    float acc[NHEAD];
#pragma unroll
    for (int h = 0; h < NHEAD; ++h) {
        uint4 u = wb[h * 64 + l];
        float a = x[0] * __uint_as_float(u.x << 16) + x[1] * __uint_as_float(u.x & 0xffff0000u)
                + x[2] * __uint_as_float(u.y << 16) + x[3] * __uint_as_float(u.y & 0xffff0000u)
                + x[4] * __uint_as_float(u.z << 16) + x[5] * __uint_as_float(u.z & 0xffff0000u)
                + x[6] * __uint_as_float(u.w << 16) + x[7] * __uint_as_float(u.w & 0xffff0000u);
        if (l < 20) a += x2 * wq[h * D_IN + 512 + l];
        acc[h] = a;
    }
#pragma unroll
    for (int h = 0; h < NHEAD; ++h) {
#pragma unroll
        for (int off = 32; off > 0; off >>= 1)
            acc[h] += __shfl_down(acc[h], off, 64);
    }
    if (l == 0) {
        float* qr = qkmp + (size_t)row * NHEAD;
#pragma unroll
        for (int h = 0; h < NHEAD; ++h) qr[h] = acc[h];
    }
}

// ------- fused attention: softmax(4 heads) -> z in LDS -> contract onto 256 cols -------
// grid (4 head-groups, 128 trees); block 256. Head-group hg owns cols [hg*256, hg*256+256).
__global__ void attn_fused_kernel(const float* __restrict__ qkmp, const bf16* __restrict__ xs,
                                  const float* __restrict__ wvt, float* __restrict__ attn_out) {
    int hg = blockIdx.x, t = blockIdx.y, tid = threadIdx.x;
    __shared__ float a4[NODES_PER_TREE * 4];   // [i*4 + hh]
    __shared__ float zs[4][536];

    // load scores for our 4 heads
    for (int l = tid; l < NODES_PER_TREE * 4; l += 256) {
        int i = l >> 2, hh = l & 3;
        a4[l] = qkmp[(size_t)t * NODES_PER_TREE * NHEAD + i * 16 + hg * 4 + hh] * 0.125f;
    }
    __syncthreads();

    // softmax: one wave per head; lane handles i=lane, i=lane+64
    int hh = tid >> 6, lane = tid & 63;
    {
        float s0 = a4[lane * 4 + hh], s1 = a4[(lane + 64) * 4 + hh];
        float m = fmaxf(s0, s1);
#pragma unroll
        for (int off = 32; off > 0; off >>= 1) m = fmaxf(m, __shfl_xor(m, off, 64));
        float e0 = expf(s0 - m), e1 = expf(s1 - m);
        float sum = e0 + e1;
#pragma unroll
        for (int off = 32; off > 0; off >>= 1) sum += __shfl_xor(sum, off, 64);
        float inv = 1.0f / sum;
        a4[lane * 4 + hh] = e0 * inv;
        a4[(lane + 64) * 4 + hh] = e1 * inv;
    }
    __syncthreads();

    // z[hh][j] = sum_i a4[i][hh] * x[t*128+i][j]; thread owns j-pair 2*tid (+ tail)
    {
        bool hasT = tid < 10;                 // tail uints 256..265 (j = 512..531)
        float az[4][2] = {};
        float at[4][2] = {};
        const bf16* xt = xs + (size_t)t * NODES_PER_TREE * D_IN;
        for (int i = 0; i < NODES_PER_TREE; ++i) {
            const unsigned int* xr = (const unsigned int*)(xt + i * D_IN);
            unsigned int u = xr[tid];
            unsigned int u2 = hasT ? xr[256 + tid] : 0u;
            float x0 = __uint_as_float(u << 16);
            float x1 = __uint_as_float(u & 0xffff0000u);
            float x2 = __uint_as_float(u2 << 16);
            float x3 = __uint_as_float(u2 & 0xffff0000u);
#pragma unroll
            for (int k = 0; k < 4; ++k) {
                float wgt = a4[i * 4 + k];
                az[k][0] += wgt * x0; az[k][1] += wgt * x1;
                at[k][0] += wgt * x2; at[k][1] += wgt * x3;
            }
        }
#pragma unroll
        for (int k = 0; k < 4; ++k) {
            *(float2*)(&zs[k][2 * tid]) = make_float2(az[k][0], az[k][1]);
            if (hasT) *(float2*)(&zs[k][512 + 2 * tid]) = make_float2(at[k][0], at[k][1]);
        }
    }
    __syncthreads();

    // contract: col c = hg*256 + tid uses head hh = tid>>6
    int c = hg * 256 + tid;
    const float* wp = wvt + c;
    float acc = 0.f;
#pragma unroll 4
    for (int j = 0; j < D_IN; ++j)
        acc += zs[hh][j] * wp[(size_t)j * D_MODEL];
    attn_out[(size_t)t * D_MODEL + c] = acc;
}

// ---------------- split-K GEMM: Cpart[split][128,N] = A[128,K-chunk] @ B[N,K-chunk]^T ----------------
// grid (N/64, splits); block 256; per-block tile 128 rows x 64 cols, K-chunk = nsb*32
__global__ void gemm_sk_kernel(const float* __restrict__ A, const float* __restrict__ B,
                               float* __restrict__ Cpart, int N, int K, int nsb) {
    __shared__ __align__(16) float As[32 * 132];
    __shared__ __align__(16) float Bs[32 * 68];
    int tid = threadIdx.x;
    int col0 = blockIdx.x * 64;
    int k0 = blockIdx.y * nsb * 32;
    float* C = Cpart + (size_t)blockIdx.y * 128 * N;

    int ty = tid >> 4, tx = tid & 15;
    int ar = tid >> 3, akk = (tid & 7) * 4;   // A staging
    int br = tid >> 2, bkk = (tid & 3) * 8;   // B staging

    float acc[8][4] = {};

    for (int s = 0; s < nsb; ++s) {
        int kb = k0 + s * 32;
#pragma unroll
        for (int p = 0; p < 4; ++p) {
            int row = ar + p * 32;
            float4 fa = *(const float4*)(A + (size_t)row * K + kb + akk);
            As[(akk + 0) * 132 + row] = fa.x;
            As[(akk + 1) * 132 + row] = fa.y;
            As[(akk + 2) * 132 + row] = fa.z;
            As[(akk + 3) * 132 + row] = fa.w;
        }
        {
            const float* bp = B + (size_t)(col0 + br) * K + kb + bkk;
            float4 f0 = *(const float4*)(bp);
            float4 f1 = *(const float4*)(bp + 4);
            Bs[(bkk + 0) * 68 + br] = f0.x; Bs[(bkk + 1) * 68 + br] = f0.y;
            Bs[(bkk + 2) * 68 + br] = f0.z; Bs[(bkk + 3) * 68 + br] = f0.w;
            Bs[(bkk + 4) * 68 + br] = f1.x; Bs[(bkk + 5) * 68 + br] = f1.y;
            Bs[(bkk + 6) * 68 + br] = f1.z; Bs[(bkk + 7) * 68 + br] = f1.w;
        }
        __syncthreads();
#pragma unroll
        for (int k = 0; k < 32; ++k) {
            float4 a0 = *(const float4*)(As + k * 132 + ty * 8);
            float4 a1 = *(const float4*)(As + k * 132 + ty * 8 + 4);
            float4 bv = *(const float4*)(Bs + k * 68 + tx * 4);
            acc[0][0] += a0.x * bv.x; acc[0][1] += a0.x * bv.y; acc[0][2] += a0.x * bv.z; acc[0][3] += a0.x * bv.w;
            acc[1][0] += a0.y * bv.x; acc[1][1] += a0.y * bv.y; acc[1][2] += a0.y * bv.z; acc[1][3] += a0.y * bv.w;
            acc[2][0] += a0.z * bv.x; acc[2][1] += a0.z * bv.y; acc[2][2] += a0.z * bv.z; acc[2][3] += a0.z * bv.w;
            acc[3][0] += a0.w * bv.x; acc[3][1] += a0.w * bv.y; acc[3][2] += a0.w * bv.z; acc[3][3] += a0.w * bv.w;
            acc[4][0] += a1.x * bv.x; acc[4][1] += a1.x * bv.y; acc[4][2] += a1.x * bv.z; acc[4][3] += a1.x * bv.w;
            acc[5][0] += a1.y * bv.x; acc[5][1] += a1.y * bv.y; acc[5][2] += a1.y * bv.z; acc[5][3] += a1.y * bv.w;
            acc[6][0] += a1.z * bv.x; acc[6][1] += a1.z * bv.y; acc[6][2] += a1.z * bv.z; acc[6][3] += a1.z * bv.w;
            acc[7][0] += a1.w * bv.x; acc[7][1] += a1.w * bv.y; acc[7][2] += a1.w * bv.z; acc[7][3] += a1.w * bv.w;
        }
        __syncthreads();
    }
#pragma unroll
    for (int r = 0; r < 8; ++r) {
        float4 v = make_float4(acc[r][0], acc[r][1], acc[r][2], acc[r][3]);
        *(float4*)(C + (size_t)(ty * 8 + r) * N + col0 + tx * 4) = v;
    }
}

// ---------------- ln_r1: reduce 8 Wo-partials + bo + qvec -> r1; LN -> l1 ----------------
__global__ void ln_r1_kernel(const float* __restrict__ po, const float* __restrict__ bo,
                             const float* __restrict__ qvec, const float* __restrict__ g,
                             const float* __restrict__ b, float* __restrict__ r1,
                             float* __restrict__ l1) {
    int t = blockIdx.x, tid = threadIdx.x;
    __shared__ float sm[16];
    float e[4];
#pragma unroll
    for (int c = 0; c < 4; ++c) {
        int j = c * 256 + tid;
        float v = bo[j] + qvec[j];
#pragma unroll
        for (int s = 0; s < 8; ++s)
            v += po[(size_t)s * NTREE * D_MODEL + (size_t)t * D_MODEL + j];
        e[c] = v;
        r1[(size_t)t * D_MODEL + j] = v;
    }
    float s = e[0] + e[1] + e[2] + e[3];
    float ss = e[0] * e[0] + e[1] * e[1] + e[2] * e[2] + e[3] * e[3];
    blockReduceSum2(s, ss, sm);
    float mu = s * (1.f / D_MODEL);
    float var = ss * (1.f / D_MODEL) - mu * mu;
    float rs = rsqrtf(var + EPS);
#pragma unroll
    for (int c = 0; c < 4; ++c) {
        int j = c * 256 + tid;
        l1[(size_t)t * D_MODEL + j] = (e[c] - mu) * rs * g[j] + b[j];
    }
}

// ---------------- gelu_reduce: h1 = gelu(sum_8 p1 + b1) ; 128x4096 elems ----------------
__global__ void gelu_reduce_kernel(const float* __restrict__ p1, const float* __restrict__ b1,
                                   float* __restrict__ h1) {
    int idx4 = (blockIdx.x * 256 + threadIdx.x) * 4;    // < 524288
    int col = idx4 & (DFF - 1);
    float4 v = *(const float4*)(b1 + col);
#pragma unroll
    for (int s = 0; s < 8; ++s) {
        float4 p = *(const float4*)(p1 + (size_t)s * NTREE * DFF + idx4);
        v.x += p.x; v.y += p.y; v.z += p.z; v.w += p.w;
    }
    v.x = gelu_exact(v.x); v.y = gelu_exact(v.y);
    v.z = gelu_exact(v.z); v.w = gelu_exact(v.w);
    *(float4*)(h1 + idx4) = v;
}

// ---------------- ln_out: reduce 16 W2-partials + b2 + r1 -> LN -> out (+zero tail) ----------------
__global__ void ln_out_kernel(const float* __restrict__ p2, const float* __restrict__ b2,
                              const float* __restrict__ r1, const float* __restrict__ g,
                              const float* __restrict__ b, float* __restrict__ out) {
    int t = blockIdx.x, tid = threadIdx.x;
    __shared__ float sm[16];
    float e[4];
#pragma unroll
    for (int c = 0; c < 4; ++c) {
        int j = c * 256 + tid;
        float v = b2[j] + r1[(size_t)t * D_MODEL + j];
#pragma unroll
        for (int s = 0; s < 16; ++s)
            v += p2[(size_t)s * NTREE * D_MODEL + (size_t)t * D_MODEL + j];
        e[c] = v;
    }
    float s = e[0] + e[1] + e[2] + e[3];
    float ss = e[0] * e[0] + e[1] * e[1] + e[2] * e[2] + e[3] * e[3];
    blockReduceSum2(s, ss, sm);
    float mu = s * (1.f / D_MODEL);
    float var = ss * (1.f / D_MODEL) - mu * mu;
    float rs = rsqrtf(var + EPS);
#pragma unroll
    for (int c = 0; c < 4; ++c) {
        int j = c * 256 + tid;
        out[(size_t)t * D_MODEL + j] = (e[c] - mu) * rs * g[j] + b[j];
    }
    if (t == 0 && tid < 128) out[(size_t)NTREE * D_MODEL + tid] = 0.f;
}

extern "C" void kernel_launch(void* const* d_in, const int* in_sizes, int n_in,
                              void* d_out, int out_size, void* d_ws, size_t ws_size,
                              hipStream_t stream) {
    const float* values = (const float*)d_in[0];
    const int* role     = (const int*)d_in[1];
    const int* bidx     = (const int*)d_in[2];
    const int* midx     = (const int*)d_in[3];
    const float* qvec   = (const float*)d_in[4];
    const float* Wk     = (const float*)d_in[5];
    const float* Wv     = (const float*)d_in[6];
    const float* Wo     = (const float*)d_in[7];
    const float* bo     = (const float*)d_in[8];
    const float* W1     = (const float*)d_in[9];
    const float* b1     = (const float*)d_in[10];
    const float* W2     = (const float*)d_in[11];
    const float* b2     = (const float*)d_in[12];
    const float* g_fil  = (const float*)d_in[13];
    const float* b_fil  = (const float*)d_in[14];
    const float* g_mha  = (const float*)d_in[15];
    const float* b_mha  = (const float*)d_in[16];
    const float* g_ff   = (const float*)d_in[17];
    const float* b_ff   = (const float*)d_in[18];
    const float* g_out  = (const float*)d_in[19];
    const float* b_out  = (const float*)d_in[20];

    // fixed region (~6.95 MB) + overlay region (~21.0 MB) = ~27.9 MB
    char* w = (char*)d_ws;
    float* wq       = (float*)(w + 0);          // 34048 -> pad 34816
    bf16*  wqb      = (bf16*) (w + 34816);      // 16*512*2 = 16384 -> 51200
    float* qkmp     = (float*)(w + 51200);      // 1048576 -> 1099776
    int*   counts   = (int*)  (w + 1099776);    // 512 -> pad 1100800
    float* attn_out = (float*)(w + 1100800);    // 524288 -> 1625088
    float* r1       = (float*)(w + 1625088);    // 524288 -> 2149376
    float* l1       = (float*)(w + 2149376);    // 524288 -> 2673664
    float* h1       = (float*)(w + 2673664);    // 2097152 -> 4770816
    float* wvt      = (float*)(w + 4770816);    // 532*1024*4 = 2179072 -> 6949888
    char*  big      = w + 6949888;              // overlay region
    // phase A (attention): xs
    bf16*  xs = (bf16*)big;                     // 16384*532*2 = 17432576
    // phase B (GEMMs, after attn_fused): partials overlay xs
    float* po = (float*)big;                    // 8  *128*1024*4 = 4194304
    float* p1 = (float*)(big + 4194304);        // 8  *128*4096*4 = 16777216 -> big+20971520
    float* p2 = (float*)big;                    // 16 *128*1024*4 = 8388608 (po/p1 dead by then)

    float* out = (float*)d_out;  // [128*1024] fp32 ++ [128] pad mask zeros

    hipMemsetAsync(counts, 0, 128 * sizeof(int), stream);

    wq_kernel<<<dim3(16, 4), 256, 0, stream>>>(qvec, Wk, wq, wqb);

    transpose_wv_kernel<<<dim3(32, 17), 256, 0, stream>>>(Wv, wvt);

    node_prep_kernel<<<N_NODES / 4, 256, 0, stream>>>(values, role, bidx, midx,
                                                      g_fil, b_fil, g_mha, b_mha,
                                                      wq, wqb, xs, qkmp, counts);

    attn_fused_kernel<<<dim3(4, NTREE), 256, 0, stream>>>(qkmp, xs, wvt, attn_out);

    // Wo: K=1024, 8 splits x (4*32=128)
    gemm_sk_kernel<<<dim3(16, 8), 256, 0, stream>>>(attn_out, Wo, po, D_MODEL, D_MODEL, 4);

    ln_r1_kernel<<<NTREE, 256, 0, stream>>>(po, bo, qvec, g_ff, b_ff, r1, l1);

    // W1: K=1024, 8 splits x 128 -> p1 [8][128][4096]
    gemm_sk_kernel<<<dim3(64, 8), 256, 0, stream>>>(l1, W1, p1, DFF, D_MODEL, 4);

    gelu_reduce_kernel<<<512, 256, 0, stream>>>(p1, b1, h1);

    // W2: K=4096, 16 splits x (8*32=256) -> p2 [16][128][1024]
    gemm_sk_kernel<<<dim3(16, 16), 256, 0, stream>>>(h1, W2, p2, D_MODEL, DFF, 8);

    ln_out_kernel<<<NTREE, 256, 0, stream>>>(p2, b2, r1, g_out, b_out, out);
}